// Round 4
// baseline (308.896 us; speedup 1.0000x reference)
//
#include <hip/hip_runtime.h>
#include <math.h>

#define BB 32
#define SS 1025
#define DD 64
#define HH 8
#define IN_D 8
#define NPATCH 1024
#define OUTD 9
#define EPSF 1e-5f
#define SD (SS*DD)        // 65600
#define SP 1056           // padded seq = 33*32
#define NQT 65            // ceil(1025/16) q-tiles
#define NCH 33            // 1056/32 t-chunks
#define VTROW 1064        // VT LDS row stride (shorts)
#define NTB 257           // blocks per batch for token/stat kernels
#define ZROW 1055         // guaranteed-zero K row (pad, zeroed by k_qkv)

typedef __attribute__((ext_vector_type(8))) short bf16x8;
typedef __attribute__((ext_vector_type(4))) float f32x4;
typedef __attribute__((ext_vector_type(4))) unsigned u32x4;

// fold softmax scale 1/sqrt(8) and exp->exp2 into Q
#define SCALE_LOG2E (0.35355339059327378f * 1.4426950408889634f)

#if __has_builtin(__builtin_amdgcn_exp2f)
__device__ __forceinline__ float exp2_fast(float x) { return __builtin_amdgcn_exp2f(x); }
#else
__device__ __forceinline__ float exp2_fast(float x) {
    float r; asm("v_exp_f32 %0, %1" : "=v"(r) : "v"(x)); return r;
}
#endif

__device__ __forceinline__ short f2bf(float f) {
    union { float f; unsigned u; } a; a.f = f;
    unsigned r = a.u + 0x7FFFu + ((a.u >> 16) & 1u);  // RNE
    return (short)(r >> 16);
}

// packed f32->bf16 (RNE); lo lands in the LOW short — matches A-frag short order.
__device__ __forceinline__ unsigned cvt_pk_bf16(float lo, float hi) {
    unsigned r;
    asm("v_cvt_pk_bf16_f32 %0, %1, %2" : "=v"(r) : "v"(lo), "v"(hi));
    return r;
}

// PV virtual-k permutation: for A-frag slot v = 8*quad + j, the P value the lane
// already holds in registers is S^T tile row t = 4*quad + (j&3) + 16*(j>>2).
// sigma(v) = bit-shuffle {b2,b4,b3,b1,b0} — bijective on [0,32). V is staged with
// the same permutation so A and B agree on k-order (MFMA k-order is arbitrary).
__device__ __forceinline__ int sigmaPV(int v) {
    return ((v & 24) >> 1) | (v & 3) | ((v & 4) << 2);
}

// ---------------- tokens = [cls; patches@w_map+b_map] + pos; per-block partial ln1 stats ----------------
__global__ void k_tokens(const float* __restrict__ images, const float* __restrict__ w_map,
                         const float* __restrict__ b_map, const float* __restrict__ cls,
                         float* __restrict__ tokens, float* __restrict__ part1,
                         float* __restrict__ partq1, float* __restrict__ sum2,
                         float* __restrict__ sumsq2) {
    int b = blockIdx.y;
    int bx = blockIdx.x;
    int idx = bx * 256 + threadIdx.x;   // [0, SD)
    int tid = threadIdx.x;
    __shared__ float recip[64];
    __shared__ float sh[512];
    if (tid < 64) {
        int j = tid;
        float div;
        if ((j & 1) == 0)
            div = powf(10000.0f, (float)j * (1.0f / 64.0f));
        else  // reference: 10000^(j-1)/64; overflow->inf -> recip 0 -> arg 0 -> cos=1 (matches f64)
            div = powf(10000.0f, (float)(j - 1)) * (1.0f / 64.0f);
        recip[j] = 1.0f / div;
    }
    __syncthreads();
    float lv = 0.f, lvv = 0.f;
    if (idx < SD) {
        int s = idx >> 6, j = idx & 63;
        float arg = (float)s * recip[j];
        float pv = (j & 1) ? __cosf(arg) : __sinf(arg);
        float v;
        if (s == 0) {
            v = cls[j];
        } else {
            const float* p = images + (size_t)b * (NPATCH * IN_D) + (size_t)(s - 1) * IN_D;
            float acc = b_map[j];
#pragma unroll
            for (int i = 0; i < IN_D; ++i) acc += p[i] * w_map[i * DD + j];
            v = acc;
        }
        v += pv;
        tokens[(size_t)b * SD + idx] = v;
        lv = v; lvv = v * v;
    }
    sh[tid] = lv; sh[256 + tid] = lvv;
    __syncthreads();
    for (int off = 128; off > 0; off >>= 1) {
        if (tid < off) { sh[tid] += sh[tid + off]; sh[256 + tid] += sh[256 + tid + off]; }
        __syncthreads();
    }
    if (tid == 0) {
        part1[b * NTB + bx] = sh[0];
        partq1[b * NTB + bx] = sh[256];
    }
    if (bx == 0) {          // zero the ln2 stat accumulators (k_attn adds later; stream-ordered)
        if (tid == 0) sum2[b] = 0.f;
        if (tid == 1) sumsq2[b] = 0.f;
    }
}

// ---------------- ln1 -> q,k,v in bf16, layout [bh][SP][8]; scale*log2e folded into q ----------------
// Last block per batch additionally zeroes kb pad rows [SS, SP) — required because
// k_attn reads K directly from global (garbage pad -> exp -> inf*0 = NaN would poison PV).
__global__ void k_qkv(const float* __restrict__ tokens, const float* __restrict__ part1,
                      const float* __restrict__ partq1, const float* __restrict__ g1,
                      const float* __restrict__ be1,
                      const float* __restrict__ wq, const float* __restrict__ bq,
                      const float* __restrict__ wk, const float* __restrict__ bk,
                      const float* __restrict__ wv, const float* __restrict__ bv,
                      short* __restrict__ qb, short* __restrict__ kb, short* __restrict__ vb) {
    int b = blockIdx.y, bx = blockIdx.x, tid = threadIdx.x;
    __shared__ float sh[512];
    __shared__ float xs[4][DD];
    __shared__ float stats[2];
    {
        float s = 0.f, ss = 0.f;
        for (int i = tid; i < NTB; i += 256) { s += part1[b * NTB + i]; ss += partq1[b * NTB + i]; }
        sh[tid] = s; sh[256 + tid] = ss;
        __syncthreads();
        for (int off = 128; off > 0; off >>= 1) {
            if (tid < off) { sh[tid] += sh[tid + off]; sh[256 + tid] += sh[256 + tid + off]; }
            __syncthreads();
        }
        if (tid == 0) {
            float mu = sh[0] / (float)SD;
            float var = sh[256] / (float)SD - mu * mu;
            stats[0] = mu;
            stats[1] = rsqrtf(var + EPSF);
        }
        __syncthreads();
    }
    int r = tid >> 6, d = tid & 63;
    int srow = bx * 4 + r;
    if (srow < SS) {
        float t = tokens[((size_t)b * SS + srow) * DD + d];
        xs[r][d] = (t - stats[0]) * stats[1] * g1[srow * DD + d] + be1[srow * DD + d];
    }
    __syncthreads();
    for (int o = tid; o < 768; o += 256) {
        int rr = o / 192;
        int rem = o % 192;
        int which = rem / 64;       // 0=q 1=k 2=v
        int he = rem % 64;
        int h = he >> 3, e = he & 7;
        int s2 = bx * 4 + rr;
        if (s2 >= SS) continue;
        const float* w = (which == 0) ? wq : (which == 1) ? wk : wv;
        const float* bias = (which == 0) ? bq : (which == 1) ? bk : bv;
        float acc = bias[he];
#pragma unroll
        for (int dd = 0; dd < 8; ++dd)
            acc += xs[rr][h * 8 + dd] * w[(h * 8 + dd) * 8 + e];
        if (which == 0) acc *= SCALE_LOG2E;
        short* dst = (which == 0) ? qb : (which == 1) ? kb : vb;
        dst[((size_t)(b * HH + h) * SP + s2) * 8 + e] = f2bf(acc);
    }
    if (bx == NTB - 1) {
        // zero K pad rows [SS, SP) for all heads of this batch: (SP-SS)*HH*8 = 15872 shorts
        for (int i = tid; i < (SP - SS) * HH * 8; i += 256) {
            int rr = i / (HH * 8);          // pad row index 0..30
            int he = i % (HH * 8);
            int hh = he >> 3, e = he & 7;
            kb[((size_t)(b * HH + hh) * SP + SS + rr) * 8 + e] = 0;
        }
    }
}

// ---------------- MFMA flash attention; CLS-row output + ln2-stat accumulation ----------------
// grid (3, HH, BB), 512 thr (8 waves).
// K read directly from global (L2); quads 1-3 broadcast the zeroed pad row ZROW.
// R12 restructure: swapped-operand QK^T (S^T = mfma(K, Q)) makes the PV A-fragment
//   lane-local — P goes registers -> exp2 -> cvt_pk -> PV MFMA with ZERO LDS ops for P.
//   V staged with matching sigmaPV permutation; 1 ds_read_b128 per chunk total.
// R13/R14: union->bitcast rewrite of the P pack — counters bit-identical, not the cause.
// R15 fix: the 162 MB WRITE_SIZE was REGISTER SPILL: __launch_bounds__(512,6) pinned the
//   allocator at 40 VGPR (same as the old LDS-P kernel) while R12 added ~12 regs of live
//   state (s0,s1,packed P across the PV MFMA) -> 1 dword/lane/chunk-iter spilled
//   (549k wave-iters x 304 B = 167 MB writes + matching fetches; MfmaUtil 7%, all waves
//   latency-bound on scratch). Relax to (512,4): ~128 VGPR budget; kernel needs ~60,
//   which still sustains 6-8 waves/SIMD. LDS (27.6 KB) caps blocks/CU at 4 anyway.
__global__ __launch_bounds__(512, 4)
void k_attn(const short* __restrict__ qb, const short* __restrict__ kb, const short* __restrict__ vb,
            const float* __restrict__ tokens, float* __restrict__ out0,
            float* __restrict__ sum2, float* __restrict__ sumsq2) {
    __shared__ __align__(16) short VTs[9 * VTROW];   // 19152 B: V^T rows [e][perm-idx]; row 8 = ones(t<SS)
    __shared__ __align__(16) float Es[8 * 256];      // 8192 B: per-wave O spill; reused for final reduction
    int h = blockIdx.y, b = blockIdx.z;
    int bh = b * HH + h;
    int tid = threadIdx.x;
    int wave = tid >> 6, lane = tid & 63;
    int col = lane & 15, quad = lane >> 4;

    bf16x8 z8 = {0, 0, 0, 0, 0, 0, 0, 0};
    {   // stage V^T k-permuted: VTs[e][32*ch + v] = V[32*ch + sigmaPV(v)][e].
        // row 8 = softmax-denominator ones (0 where t >= SS: excludes pad P=1 terms).
        const bf16x8* vg = (const bf16x8*)(vb + (size_t)bh * SP * 8);
        for (int i = tid; i < SP; i += 512) {
            int t = (i & ~31) | sigmaPV(i & 31);
            if (t < SS) {
                bf16x8 row = vg[t];
#pragma unroll
                for (int e = 0; e < 8; ++e) VTs[e * VTROW + i] = row[e];
                VTs[8 * VTROW + i] = (short)0x3F80;   // bf16 1.0
            } else {
#pragma unroll
                for (int e = 0; e < 9; ++e) VTs[e * VTROW + i] = 0;
            }
        }
    }
    __syncthreads();

    // K A-frag straight from global: quad0 lanes walk rows t0+col / t0+col+16;
    // quads 1-3 read the zeroed pad row (same address across lanes -> broadcast).
    const short* kg = kb + (size_t)bh * SP * 8;
    const short* kp0 = kg + ((quad == 0) ? col * 8 : ZROW * 8);
    const int kstep = (quad == 0) ? 256 : 0;     // shorts per 32-t chunk
    const int koff16 = (quad == 0) ? 128 : 0;
    // V B-frag: lane col -> VT row e; cols 9-15 read the ones row (their O columns
    // are computed but never read in the epilogue — harmless finite values)
    const short* vbase_l = VTs + (col < 9 ? col : 8) * VTROW + quad * 8;
    float* Ef = Es + wave * 256;

    float lsum = 0.f, lssq = 0.f;
    int slot = blockIdx.x * 8 + wave;   // 0..23

    for (int qt = slot; qt < NQT; qt += 24) {
        bf16x8 qfrag = z8;
        if (quad == 0) qfrag = *(const bf16x8*)(qb + ((size_t)bh * SP + qt * 16 + col) * 8);
        f32x4 o = {0.f, 0.f, 0.f, 0.f};
        const f32x4 zz = {0.f, 0.f, 0.f, 0.f};
        const short* kptr = kp0;
        bf16x8 ka = *(const bf16x8*)kptr;                    // K(0) prefetch
        bf16x8 kb_ = *(const bf16x8*)(kptr + koff16);
        for (int ch = 0; ch < NCH; ++ch) {
            bf16x8 vf = *(const bf16x8*)(vbase_l + ch * 32); // the ONLY LDS op in the loop
            f32x4 s0 = __builtin_amdgcn_mfma_f32_16x16x32_bf16(ka, qfrag, zz, 0, 0, 0);
            f32x4 s1 = __builtin_amdgcn_mfma_f32_16x16x32_bf16(kb_, qfrag, zz, 0, 0, 0);
            if (ch + 1 < NCH) {          // prefetch K(ch+1) while exp/cvt/PV of ch run
                kptr += kstep;
                ka = *(const bf16x8*)kptr;
                kb_ = *(const bf16x8*)(kptr + koff16);
            }
            // P stays in registers: named SSA values -> u32x4 -> bit_cast (no memory object)
            unsigned p0 = cvt_pk_bf16(exp2_fast(s0[0]), exp2_fast(s0[1]));
            unsigned p1 = cvt_pk_bf16(exp2_fast(s0[2]), exp2_fast(s0[3]));
            unsigned p2 = cvt_pk_bf16(exp2_fast(s1[0]), exp2_fast(s1[1]));
            unsigned p3 = cvt_pk_bf16(exp2_fast(s1[2]), exp2_fast(s1[3]));
            u32x4 pu = {p0, p1, p2, p3};
            bf16x8 pv = __builtin_bit_cast(bf16x8, pu);
            o = __builtin_amdgcn_mfma_f32_16x16x32_bf16(pv, vf, o, 0, 0, 0);
        }
        // epilogue: spill O via per-wave scratch (col 8 = softmax denom l).
        // lane(col,quad) holds O[q=4*quad+r][e=col].
#pragma unroll
        for (int r = 0; r < 4; ++r) Ef[(quad * 4 + r) * 16 + col] = o[r];
#pragma unroll
        for (int pass = 0; pass < 2; ++pass) {
            int idx = lane + pass * 64;    // 16q x 8e
            int qq = idx >> 3, e = idx & 7;
            int qg = qt * 16 + qq;
            if (qg < SS) {
                float num = Ef[qq * 16 + e];
                float l = Ef[qq * 16 + 8];
                float ov = tokens[((size_t)b * SS + qg) * DD + h * 8 + e] + num / l;
                lsum += ov; lssq += ov * ov;
                if (qg == 0) out0[b * DD + h * 8 + e] = ov;
            }
        }
    }

    __syncthreads();
    Es[tid] = lsum; Es[512 + tid] = lssq;    // per-wave scratch dead; reuse for reduction
    __syncthreads();
    for (int off = 256; off > 0; off >>= 1) {
        if (tid < off) { Es[tid] += Es[tid + off]; Es[512 + tid] += Es[512 + tid + off]; }
        __syncthreads();
    }
    if (tid == 0) {
        atomicAdd(&sum2[b], Es[0]);
        atomicAdd(&sumsq2[b], Es[512]);
    }
}

// ---------------- final: ln2(row0) -> MLP(+relu) -> residual -> head -> softmax ----------------
__global__ void k_final(const float* __restrict__ out0, const float* __restrict__ sum2,
                        const float* __restrict__ sumsq2, const float* __restrict__ g2,
                        const float* __restrict__ be2, const float* __restrict__ w_enc,
                        const float* __restrict__ b_enc, const float* __restrict__ w_out,
                        const float* __restrict__ b_out, float* __restrict__ out) {
    int b = blockIdx.x;
    int tid = threadIdx.x;  // 64
    __shared__ float xn[DD], hsh[DD], logit[OUTD];
    float n = (float)SD;
    float mu = sum2[b] / n;
    float var = sumsq2[b] / n - mu * mu;
    float rs = rsqrtf(var + EPSF);
    float o = out0[b * DD + tid];
    xn[tid] = (o - mu) * rs * g2[tid] + be2[tid];
    __syncthreads();
    float acc = b_enc[tid];
#pragma unroll
    for (int d = 0; d < DD; ++d) acc += xn[d] * w_enc[d * DD + tid];
    hsh[tid] = o + fmaxf(acc, 0.f);
    __syncthreads();
    if (tid < OUTD) {
        float a = b_out[tid];
#pragma unroll
        for (int d = 0; d < DD; ++d) a += hsh[d] * w_out[d * OUTD + tid];
        logit[tid] = a;
    }
    __syncthreads();
    if (tid == 0) {
        float m = logit[0];
        for (int i = 1; i < OUTD; ++i) m = fmaxf(m, logit[i]);
        float p[OUTD]; float ssum = 0.f;
        for (int i = 0; i < OUTD; ++i) { p[i] = expf(logit[i] - m); ssum += p[i]; }
        for (int i = 0; i < OUTD; ++i) out[b * OUTD + i] = p[i] / ssum;
    }
}

extern "C" void kernel_launch(void* const* d_in, const int* in_sizes, int n_in,
                              void* d_out, int out_size, void* d_ws, size_t ws_size,
                              hipStream_t stream) {
    const float* images = (const float*)d_in[0];
    const float* w_map  = (const float*)d_in[1];
    const float* b_map  = (const float*)d_in[2];
    const float* cls    = (const float*)d_in[3];
    const float* g1     = (const float*)d_in[4];
    const float* be1    = (const float*)d_in[5];
    const float* wq     = (const float*)d_in[6];
    const float* bq     = (const float*)d_in[7];
    const float* wk     = (const float*)d_in[8];
    const float* bk     = (const float*)d_in[9];
    const float* wv     = (const float*)d_in[10];
    const float* bv     = (const float*)d_in[11];
    const float* g2     = (const float*)d_in[12];
    const float* be2    = (const float*)d_in[13];
    const float* w_enc  = (const float*)d_in[14];
    const float* b_enc  = (const float*)d_in[15];
    const float* w_out  = (const float*)d_in[16];
    const float* b_out  = (const float*)d_in[17];
    float* out = (float*)d_out;

    float* ws = (float*)d_ws;
    size_t off = 0;
    float* tokens = ws + off; off += (size_t)BB * SD;
    float* out0   = ws + off; off += BB * DD;
    float* part1  = ws + off; off += BB * NTB;
    float* partq1 = ws + off; off += BB * NTB;
    float* sum2   = ws + off; off += BB;
    float* sumsq2 = ws + off; off += BB;
    short* qb = (short*)(ws + off); off += (size_t)BB * HH * SP * 8 / 2;
    short* kb = (short*)(ws + off); off += (size_t)BB * HH * SP * 8 / 2;
    short* vb = (short*)(ws + off); off += (size_t)BB * HH * SP * 8 / 2;

    k_tokens<<<dim3(NTB, BB), 256, 0, stream>>>(images, w_map, b_map, cls, tokens,
                                                part1, partq1, sum2, sumsq2);
    k_qkv<<<dim3(NTB, BB), 256, 0, stream>>>(tokens, part1, partq1, g1, be1,
                                             wq, bq, wk, bk, wv, bv, qb, kb, vb);
    k_attn<<<dim3(3, HH, BB), 512, 0, stream>>>(qb, kb, vb, tokens, out0, sum2, sumsq2);
    k_final<<<BB, DD, 0, stream>>>(out0, sum2, sumsq2, g2, be2, w_enc, b_enc, w_out, b_out, out);
}

// Round 5
// 175.000 us; speedup vs baseline: 1.7651x; 1.7651x over previous
//
#include <hip/hip_runtime.h>
#include <math.h>

#define BB 32
#define SS 1025
#define DD 64
#define HH 8
#define IN_D 8
#define NPATCH 1024
#define OUTD 9
#define EPSF 1e-5f
#define SD (SS*DD)        // 65600
#define SP 1056           // padded seq = 33*32
#define NQT 65            // ceil(1025/16) q-tiles
#define NCH 33            // 1056/32 t-chunks
#define VTROW 1064        // VT LDS row stride (shorts)
#define NTB 257           // blocks per batch for token/stat kernels
#define ZROW 1055         // guaranteed-zero K row (pad, zeroed by k_qkv)

typedef __attribute__((ext_vector_type(8))) short bf16x8;
typedef __attribute__((ext_vector_type(4))) float f32x4;
typedef __attribute__((ext_vector_type(4))) unsigned u32x4;

// fold softmax scale 1/sqrt(8) and exp->exp2 into Q
#define SCALE_LOG2E (0.35355339059327378f * 1.4426950408889634f)

#if __has_builtin(__builtin_amdgcn_exp2f)
__device__ __forceinline__ float exp2_fast(float x) { return __builtin_amdgcn_exp2f(x); }
#else
__device__ __forceinline__ float exp2_fast(float x) {
    float r; asm("v_exp_f32 %0, %1" : "=v"(r) : "v"(x)); return r;
}
#endif

__device__ __forceinline__ short f2bf(float f) {
    union { float f; unsigned u; } a; a.f = f;
    unsigned r = a.u + 0x7FFFu + ((a.u >> 16) & 1u);  // RNE
    return (short)(r >> 16);
}

// packed f32->bf16 (RNE); lo lands in the LOW short — matches A-frag short order.
__device__ __forceinline__ unsigned cvt_pk_bf16(float lo, float hi) {
    unsigned r;
    asm("v_cvt_pk_bf16_f32 %0, %1, %2" : "=v"(r) : "v"(lo), "v"(hi));
    return r;
}

// PV virtual-k permutation: for A-frag slot v = 8*quad + j, the P value the lane
// already holds in registers is S^T tile row t = 4*quad + (j&3) + 16*(j>>2).
// sigma(v) = bit-shuffle {b2,b4,b3,b1,b0} — bijective on [0,32). V is staged with
// the same permutation so A and B agree on k-order (MFMA k-order is arbitrary).
__device__ __forceinline__ int sigmaPV(int v) {
    return ((v & 24) >> 1) | (v & 3) | ((v & 4) << 2);
}

// ---------------- tokens = [cls; patches@w_map+b_map] + pos; per-block partial ln1 stats ----------------
__global__ void k_tokens(const float* __restrict__ images, const float* __restrict__ w_map,
                         const float* __restrict__ b_map, const float* __restrict__ cls,
                         float* __restrict__ tokens, float* __restrict__ part1,
                         float* __restrict__ partq1, float* __restrict__ sum2,
                         float* __restrict__ sumsq2) {
    int b = blockIdx.y;
    int bx = blockIdx.x;
    int idx = bx * 256 + threadIdx.x;   // [0, SD)
    int tid = threadIdx.x;
    __shared__ float recip[64];
    __shared__ float sh[512];
    if (tid < 64) {
        int j = tid;
        float div;
        if ((j & 1) == 0)
            div = powf(10000.0f, (float)j * (1.0f / 64.0f));
        else  // reference: 10000^(j-1)/64; overflow->inf -> recip 0 -> arg 0 -> cos=1 (matches f64)
            div = powf(10000.0f, (float)(j - 1)) * (1.0f / 64.0f);
        recip[j] = 1.0f / div;
    }
    __syncthreads();
    float lv = 0.f, lvv = 0.f;
    if (idx < SD) {
        int s = idx >> 6, j = idx & 63;
        float arg = (float)s * recip[j];
        float pv = (j & 1) ? __cosf(arg) : __sinf(arg);
        float v;
        if (s == 0) {
            v = cls[j];
        } else {
            const float* p = images + (size_t)b * (NPATCH * IN_D) + (size_t)(s - 1) * IN_D;
            float acc = b_map[j];
#pragma unroll
            for (int i = 0; i < IN_D; ++i) acc += p[i] * w_map[i * DD + j];
            v = acc;
        }
        v += pv;
        tokens[(size_t)b * SD + idx] = v;
        lv = v; lvv = v * v;
    }
    sh[tid] = lv; sh[256 + tid] = lvv;
    __syncthreads();
    for (int off = 128; off > 0; off >>= 1) {
        if (tid < off) { sh[tid] += sh[tid + off]; sh[256 + tid] += sh[256 + tid + off]; }
        __syncthreads();
    }
    if (tid == 0) {
        part1[b * NTB + bx] = sh[0];
        partq1[b * NTB + bx] = sh[256];
    }
    if (bx == 0) {          // zero the ln2 stat accumulators (k_attn adds later; stream-ordered)
        if (tid == 0) sum2[b] = 0.f;
        if (tid == 1) sumsq2[b] = 0.f;
    }
}

// ---------------- ln1 -> q,k,v in bf16, layout [bh][SP][8]; scale*log2e folded into q ----------------
// Last block per batch additionally zeroes kb pad rows [SS, SP) — required because
// k_attn reads K directly from global (garbage pad -> exp -> inf*0 = NaN would poison PV).
__global__ void k_qkv(const float* __restrict__ tokens, const float* __restrict__ part1,
                      const float* __restrict__ partq1, const float* __restrict__ g1,
                      const float* __restrict__ be1,
                      const float* __restrict__ wq, const float* __restrict__ bq,
                      const float* __restrict__ wk, const float* __restrict__ bk,
                      const float* __restrict__ wv, const float* __restrict__ bv,
                      short* __restrict__ qb, short* __restrict__ kb, short* __restrict__ vb) {
    int b = blockIdx.y, bx = blockIdx.x, tid = threadIdx.x;
    __shared__ float sh[512];
    __shared__ float xs[4][DD];
    __shared__ float stats[2];
    {
        float s = 0.f, ss = 0.f;
        for (int i = tid; i < NTB; i += 256) { s += part1[b * NTB + i]; ss += partq1[b * NTB + i]; }
        sh[tid] = s; sh[256 + tid] = ss;
        __syncthreads();
        for (int off = 128; off > 0; off >>= 1) {
            if (tid < off) { sh[tid] += sh[tid + off]; sh[256 + tid] += sh[256 + tid + off]; }
            __syncthreads();
        }
        if (tid == 0) {
            float mu = sh[0] / (float)SD;
            float var = sh[256] / (float)SD - mu * mu;
            stats[0] = mu;
            stats[1] = rsqrtf(var + EPSF);
        }
        __syncthreads();
    }
    int r = tid >> 6, d = tid & 63;
    int srow = bx * 4 + r;
    if (srow < SS) {
        float t = tokens[((size_t)b * SS + srow) * DD + d];
        xs[r][d] = (t - stats[0]) * stats[1] * g1[srow * DD + d] + be1[srow * DD + d];
    }
    __syncthreads();
    for (int o = tid; o < 768; o += 256) {
        int rr = o / 192;
        int rem = o % 192;
        int which = rem / 64;       // 0=q 1=k 2=v
        int he = rem % 64;
        int h = he >> 3, e = he & 7;
        int s2 = bx * 4 + rr;
        if (s2 >= SS) continue;
        const float* w = (which == 0) ? wq : (which == 1) ? wk : wv;
        const float* bias = (which == 0) ? bq : (which == 1) ? bk : bv;
        float acc = bias[he];
#pragma unroll
        for (int dd = 0; dd < 8; ++dd)
            acc += xs[rr][h * 8 + dd] * w[(h * 8 + dd) * 8 + e];
        if (which == 0) acc *= SCALE_LOG2E;
        short* dst = (which == 0) ? qb : (which == 1) ? kb : vb;
        dst[((size_t)(b * HH + h) * SP + s2) * 8 + e] = f2bf(acc);
    }
    if (bx == NTB - 1) {
        // zero K pad rows [SS, SP) for all heads of this batch: (SP-SS)*HH*8 = 15872 shorts
        for (int i = tid; i < (SP - SS) * HH * 8; i += 256) {
            int rr = i / (HH * 8);          // pad row index 0..30
            int he = i % (HH * 8);
            int hh = he >> 3, e = he & 7;
            kb[((size_t)(b * HH + hh) * SP + SS + rr) * 8 + e] = 0;
        }
    }
}

// ---------------- MFMA flash attention; CLS-row output + ln2-stat accumulation ----------------
// grid (3, HH, BB), 512 thr (8 waves).
// K read directly from global (L2); quads 1-3 broadcast the zeroed pad row ZROW.
// R12 restructure: swapped-operand QK^T (S^T = mfma(K, Q)) makes the PV A-fragment
//   lane-local — P goes registers -> exp2 -> cvt_pk -> PV MFMA with ZERO LDS ops for P.
//   V staged with matching sigmaPV permutation; 1 ds_read_b128 per chunk total.
// R13/R14: union->bitcast rewrite — counters identical; idiom was not the cause.
// R15: launch_bounds (512,6)->(512,4): spill halved (167->91 MB) but VGPR pinned at
//   exactly 64 = HALF the 128 budget -> allocator's even VGPR/AGPR split; arch side
//   still overflowing. Hand-count of one iteration's live state is ~48 regs, so the
//   overflow must come from the compiler UNROLLING/pipelining the chunk loop (two
//   iterations of s0/s1/pv/vf live; NCH=33 + conditional prefetch branch is the
//   classic trigger). dur worsened 142->187 because occupancy fell 52->32%.
// R16 fix: (a) #pragma clang loop unroll(disable) on the chunk loop — one copy of
//   iteration state; (b) branchless rotated prefetch (final iteration dead-loads one
//   chunk past the K slice — lands in the adjacent vb workspace region, never consumed;
//   quads 1-3 keep re-reading the zero row). Target: zero scratch at <=64 arch VGPRs.
__global__ __launch_bounds__(512, 4)
void k_attn(const short* __restrict__ qb, const short* __restrict__ kb, const short* __restrict__ vb,
            const float* __restrict__ tokens, float* __restrict__ out0,
            float* __restrict__ sum2, float* __restrict__ sumsq2) {
    __shared__ __align__(16) short VTs[9 * VTROW];   // 19152 B: V^T rows [e][perm-idx]; row 8 = ones(t<SS)
    __shared__ __align__(16) float Es[8 * 256];      // 8192 B: per-wave O spill; reused for final reduction
    int h = blockIdx.y, b = blockIdx.z;
    int bh = b * HH + h;
    int tid = threadIdx.x;
    int wave = tid >> 6, lane = tid & 63;
    int col = lane & 15, quad = lane >> 4;

    bf16x8 z8 = {0, 0, 0, 0, 0, 0, 0, 0};
    {   // stage V^T k-permuted: VTs[e][32*ch + v] = V[32*ch + sigmaPV(v)][e].
        // row 8 = softmax-denominator ones (0 where t >= SS: excludes pad P=1 terms).
        const bf16x8* vg = (const bf16x8*)(vb + (size_t)bh * SP * 8);
        for (int i = tid; i < SP; i += 512) {
            int t = (i & ~31) | sigmaPV(i & 31);
            if (t < SS) {
                bf16x8 row = vg[t];
#pragma unroll
                for (int e = 0; e < 8; ++e) VTs[e * VTROW + i] = row[e];
                VTs[8 * VTROW + i] = (short)0x3F80;   // bf16 1.0
            } else {
#pragma unroll
                for (int e = 0; e < 9; ++e) VTs[e * VTROW + i] = 0;
            }
        }
    }
    __syncthreads();

    // K A-frag straight from global: quad0 lanes walk rows t0+col / t0+col+16;
    // quads 1-3 read the zeroed pad row (same address across lanes -> broadcast).
    const short* kg = kb + (size_t)bh * SP * 8;
    const short* kp0 = kg + ((quad == 0) ? col * 8 : ZROW * 8);
    const int kstep = (quad == 0) ? 256 : 0;     // shorts per 32-t chunk
    const int koff16 = (quad == 0) ? 128 : 0;
    // V B-frag: lane col -> VT row e; cols 9-15 read the ones row (their O columns
    // are computed but never read in the epilogue — harmless finite values)
    const short* vbase_l = VTs + (col < 9 ? col : 8) * VTROW + quad * 8;
    float* Ef = Es + wave * 256;

    float lsum = 0.f, lssq = 0.f;
    int slot = blockIdx.x * 8 + wave;   // 0..23

    for (int qt = slot; qt < NQT; qt += 24) {
        bf16x8 qfrag = z8;
        if (quad == 0) qfrag = *(const bf16x8*)(qb + ((size_t)bh * SP + qt * 16 + col) * 8);
        f32x4 o = {0.f, 0.f, 0.f, 0.f};
        const f32x4 zz = {0.f, 0.f, 0.f, 0.f};
        bf16x8 ka = *(const bf16x8*)kp0;                 // K(0) prefetch
        bf16x8 kb_ = *(const bf16x8*)(kp0 + koff16);
        const short* kptr = kp0 + kstep;                 // points at chunk ch+1
        const short* vptr = vbase_l;
#pragma clang loop unroll(disable)
        for (int ch = 0; ch < NCH; ++ch) {
            bf16x8 vf = *(const bf16x8*)vptr;            // the ONLY LDS op in the loop
            vptr += 32;
            f32x4 s0 = __builtin_amdgcn_mfma_f32_16x16x32_bf16(ka, qfrag, zz, 0, 0, 0);
            f32x4 s1 = __builtin_amdgcn_mfma_f32_16x16x32_bf16(kb_, qfrag, zz, 0, 0, 0);
            // branchless rotated prefetch: last iteration dead-loads into the adjacent
            // workspace region (allocated, never consumed) — no dual-version live ranges
            ka = *(const bf16x8*)kptr;
            kb_ = *(const bf16x8*)(kptr + koff16);
            kptr += kstep;
            unsigned p0 = cvt_pk_bf16(exp2_fast(s0[0]), exp2_fast(s0[1]));
            unsigned p1 = cvt_pk_bf16(exp2_fast(s0[2]), exp2_fast(s0[3]));
            unsigned p2 = cvt_pk_bf16(exp2_fast(s1[0]), exp2_fast(s1[1]));
            unsigned p3 = cvt_pk_bf16(exp2_fast(s1[2]), exp2_fast(s1[3]));
            u32x4 pu = {p0, p1, p2, p3};
            o = __builtin_amdgcn_mfma_f32_16x16x32_bf16(__builtin_bit_cast(bf16x8, pu), vf, o, 0, 0, 0);
        }
        // epilogue: spill O via per-wave scratch (col 8 = softmax denom l).
        // lane(col,quad) holds O[q=4*quad+r][e=col].
#pragma unroll
        for (int r = 0; r < 4; ++r) Ef[(quad * 4 + r) * 16 + col] = o[r];
#pragma unroll
        for (int pass = 0; pass < 2; ++pass) {
            int idx = lane + pass * 64;    // 16q x 8e
            int qq = idx >> 3, e = idx & 7;
            int qg = qt * 16 + qq;
            if (qg < SS) {
                float num = Ef[qq * 16 + e];
                float l = Ef[qq * 16 + 8];
                float ov = tokens[((size_t)b * SS + qg) * DD + h * 8 + e] + num / l;
                lsum += ov; lssq += ov * ov;
                if (qg == 0) out0[b * DD + h * 8 + e] = ov;
            }
        }
    }

    __syncthreads();
    Es[tid] = lsum; Es[512 + tid] = lssq;    // per-wave scratch dead; reuse for reduction
    __syncthreads();
    for (int off = 256; off > 0; off >>= 1) {
        if (tid < off) { Es[tid] += Es[tid + off]; Es[512 + tid] += Es[512 + tid + off]; }
        __syncthreads();
    }
    if (tid == 0) {
        atomicAdd(&sum2[b], Es[0]);
        atomicAdd(&sumsq2[b], Es[512]);
    }
}

// ---------------- final: ln2(row0) -> MLP(+relu) -> residual -> head -> softmax ----------------
__global__ void k_final(const float* __restrict__ out0, const float* __restrict__ sum2,
                        const float* __restrict__ sumsq2, const float* __restrict__ g2,
                        const float* __restrict__ be2, const float* __restrict__ w_enc,
                        const float* __restrict__ b_enc, const float* __restrict__ w_out,
                        const float* __restrict__ b_out, float* __restrict__ out) {
    int b = blockIdx.x;
    int tid = threadIdx.x;  // 64
    __shared__ float xn[DD], hsh[DD], logit[OUTD];
    float n = (float)SD;
    float mu = sum2[b] / n;
    float var = sumsq2[b] / n - mu * mu;
    float rs = rsqrtf(var + EPSF);
    float o = out0[b * DD + tid];
    xn[tid] = (o - mu) * rs * g2[tid] + be2[tid];
    __syncthreads();
    float acc = b_enc[tid];
#pragma unroll
    for (int d = 0; d < DD; ++d) acc += xn[d] * w_enc[d * DD + tid];
    hsh[tid] = o + fmaxf(acc, 0.f);
    __syncthreads();
    if (tid < OUTD) {
        float a = b_out[tid];
#pragma unroll
        for (int d = 0; d < DD; ++d) a += hsh[d] * w_out[d * OUTD + tid];
        logit[tid] = a;
    }
    __syncthreads();
    if (tid == 0) {
        float m = logit[0];
        for (int i = 1; i < OUTD; ++i) m = fmaxf(m, logit[i]);
        float p[OUTD]; float ssum = 0.f;
        for (int i = 0; i < OUTD; ++i) { p[i] = expf(logit[i] - m); ssum += p[i]; }
        for (int i = 0; i < OUTD; ++i) out[b * OUTD + i] = p[i] / ssum;
    }
}

extern "C" void kernel_launch(void* const* d_in, const int* in_sizes, int n_in,
                              void* d_out, int out_size, void* d_ws, size_t ws_size,
                              hipStream_t stream) {
    const float* images = (const float*)d_in[0];
    const float* w_map  = (const float*)d_in[1];
    const float* b_map  = (const float*)d_in[2];
    const float* cls    = (const float*)d_in[3];
    const float* g1     = (const float*)d_in[4];
    const float* be1    = (const float*)d_in[5];
    const float* wq     = (const float*)d_in[6];
    const float* bq     = (const float*)d_in[7];
    const float* wk     = (const float*)d_in[8];
    const float* bk     = (const float*)d_in[9];
    const float* wv     = (const float*)d_in[10];
    const float* bv     = (const float*)d_in[11];
    const float* g2     = (const float*)d_in[12];
    const float* be2    = (const float*)d_in[13];
    const float* w_enc  = (const float*)d_in[14];
    const float* b_enc  = (const float*)d_in[15];
    const float* w_out  = (const float*)d_in[16];
    const float* b_out  = (const float*)d_in[17];
    float* out = (float*)d_out;

    float* ws = (float*)d_ws;
    size_t off = 0;
    float* tokens = ws + off; off += (size_t)BB * SD;
    float* out0   = ws + off; off += BB * DD;
    float* part1  = ws + off; off += BB * NTB;
    float* partq1 = ws + off; off += BB * NTB;
    float* sum2   = ws + off; off += BB;
    float* sumsq2 = ws + off; off += BB;
    short* qb = (short*)(ws + off); off += (size_t)BB * HH * SP * 8 / 2;
    short* kb = (short*)(ws + off); off += (size_t)BB * HH * SP * 8 / 2;
    short* vb = (short*)(ws + off); off += (size_t)BB * HH * SP * 8 / 2;

    k_tokens<<<dim3(NTB, BB), 256, 0, stream>>>(images, w_map, b_map, cls, tokens,
                                                part1, partq1, sum2, sumsq2);
    k_qkv<<<dim3(NTB, BB), 256, 0, stream>>>(tokens, part1, partq1, g1, be1,
                                             wq, bq, wk, bk, wv, bv, qb, kb, vb);
    k_attn<<<dim3(3, HH, BB), 512, 0, stream>>>(qb, kb, vb, tokens, out0, sum2, sumsq2);
    k_final<<<BB, DD, 0, stream>>>(out0, sum2, sumsq2, g2, be2, w_enc, b_enc, w_out, b_out, out);
}

// Round 6
// 174.880 us; speedup vs baseline: 1.7663x; 1.0007x over previous
//
#include <hip/hip_runtime.h>
#include <math.h>

#define BB 32
#define SS 1025
#define DD 64
#define HH 8
#define IN_D 8
#define NPATCH 1024
#define OUTD 9
#define EPSF 1e-5f
#define SD (SS*DD)        // 65600
#define SP 1056           // padded seq = 33*32
#define NQT 65            // ceil(1025/16) q-tiles
#define NCH 33            // 1056/32 t-chunks
#define VTROW 1064        // VT LDS row stride (shorts)
#define NTB 257           // blocks per batch for token/stat kernels
#define ZROW 1055         // guaranteed-zero K row (pad, zeroed by k_qkv)

typedef __attribute__((ext_vector_type(8))) short bf16x8;
typedef __attribute__((ext_vector_type(4))) float f32x4;
typedef __attribute__((ext_vector_type(4))) unsigned u32x4;

// fold softmax scale 1/sqrt(8) and exp->exp2 into Q
#define SCALE_LOG2E (0.35355339059327378f * 1.4426950408889634f)

#if __has_builtin(__builtin_amdgcn_exp2f)
__device__ __forceinline__ float exp2_fast(float x) { return __builtin_amdgcn_exp2f(x); }
#else
__device__ __forceinline__ float exp2_fast(float x) {
    float r; asm("v_exp_f32 %0, %1" : "=v"(r) : "v"(x)); return r;
}
#endif

__device__ __forceinline__ short f2bf(float f) {
    union { float f; unsigned u; } a; a.f = f;
    unsigned r = a.u + 0x7FFFu + ((a.u >> 16) & 1u);  // RNE
    return (short)(r >> 16);
}

// packed f32->bf16 (RNE); lo lands in the LOW short — matches A-frag short order.
__device__ __forceinline__ unsigned cvt_pk_bf16(float lo, float hi) {
    unsigned r;
    asm("v_cvt_pk_bf16_f32 %0, %1, %2" : "=v"(r) : "v"(lo), "v"(hi));
    return r;
}

// PV virtual-k permutation: for A-frag slot v = 8*quad + j, the P value the lane
// already holds in registers is S^T tile row t = 4*quad + (j&3) + 16*(j>>2).
// sigma(v) = bit-shuffle {b2,b4,b3,b1,b0} — bijective on [0,32). V is staged with
// the same permutation so A and B agree on k-order (MFMA k-order is arbitrary).
__device__ __forceinline__ int sigmaPV(int v) {
    return ((v & 24) >> 1) | (v & 3) | ((v & 4) << 2);
}

// ---------------- tokens = [cls; patches@w_map+b_map] + pos; per-block partial ln1 stats ----------------
__global__ void k_tokens(const float* __restrict__ images, const float* __restrict__ w_map,
                         const float* __restrict__ b_map, const float* __restrict__ cls,
                         float* __restrict__ tokens, float* __restrict__ part1,
                         float* __restrict__ partq1, float* __restrict__ sum2,
                         float* __restrict__ sumsq2) {
    int b = blockIdx.y;
    int bx = blockIdx.x;
    int idx = bx * 256 + threadIdx.x;   // [0, SD)
    int tid = threadIdx.x;
    __shared__ float recip[64];
    __shared__ float sh[512];
    if (tid < 64) {
        int j = tid;
        float div;
        if ((j & 1) == 0)
            div = powf(10000.0f, (float)j * (1.0f / 64.0f));
        else  // reference: 10000^(j-1)/64; overflow->inf -> recip 0 -> arg 0 -> cos=1 (matches f64)
            div = powf(10000.0f, (float)(j - 1)) * (1.0f / 64.0f);
        recip[j] = 1.0f / div;
    }
    __syncthreads();
    float lv = 0.f, lvv = 0.f;
    if (idx < SD) {
        int s = idx >> 6, j = idx & 63;
        float arg = (float)s * recip[j];
        float pv = (j & 1) ? __cosf(arg) : __sinf(arg);
        float v;
        if (s == 0) {
            v = cls[j];
        } else {
            const float* p = images + (size_t)b * (NPATCH * IN_D) + (size_t)(s - 1) * IN_D;
            float acc = b_map[j];
#pragma unroll
            for (int i = 0; i < IN_D; ++i) acc += p[i] * w_map[i * DD + j];
            v = acc;
        }
        v += pv;
        tokens[(size_t)b * SD + idx] = v;
        lv = v; lvv = v * v;
    }
    sh[tid] = lv; sh[256 + tid] = lvv;
    __syncthreads();
    for (int off = 128; off > 0; off >>= 1) {
        if (tid < off) { sh[tid] += sh[tid + off]; sh[256 + tid] += sh[256 + tid + off]; }
        __syncthreads();
    }
    if (tid == 0) {
        part1[b * NTB + bx] = sh[0];
        partq1[b * NTB + bx] = sh[256];
    }
    if (bx == 0) {          // zero the ln2 stat accumulators (k_attn adds later; stream-ordered)
        if (tid == 0) sum2[b] = 0.f;
        if (tid == 1) sumsq2[b] = 0.f;
    }
}

// ---------------- ln1 -> q,k,v in bf16, layout [bh][SP][8]; scale*log2e folded into q ----------------
// Last block per batch additionally zeroes kb pad rows [SS, SP) — required because
// k_attn reads K directly from global (garbage pad -> exp -> inf*0 = NaN would poison PV).
__global__ void k_qkv(const float* __restrict__ tokens, const float* __restrict__ part1,
                      const float* __restrict__ partq1, const float* __restrict__ g1,
                      const float* __restrict__ be1,
                      const float* __restrict__ wq, const float* __restrict__ bq,
                      const float* __restrict__ wk, const float* __restrict__ bk,
                      const float* __restrict__ wv, const float* __restrict__ bv,
                      short* __restrict__ qb, short* __restrict__ kb, short* __restrict__ vb) {
    int b = blockIdx.y, bx = blockIdx.x, tid = threadIdx.x;
    __shared__ float sh[512];
    __shared__ float xs[4][DD];
    __shared__ float stats[2];
    {
        float s = 0.f, ss = 0.f;
        for (int i = tid; i < NTB; i += 256) { s += part1[b * NTB + i]; ss += partq1[b * NTB + i]; }
        sh[tid] = s; sh[256 + tid] = ss;
        __syncthreads();
        for (int off = 128; off > 0; off >>= 1) {
            if (tid < off) { sh[tid] += sh[tid + off]; sh[256 + tid] += sh[256 + tid + off]; }
            __syncthreads();
        }
        if (tid == 0) {
            float mu = sh[0] / (float)SD;
            float var = sh[256] / (float)SD - mu * mu;
            stats[0] = mu;
            stats[1] = rsqrtf(var + EPSF);
        }
        __syncthreads();
    }
    int r = tid >> 6, d = tid & 63;
    int srow = bx * 4 + r;
    if (srow < SS) {
        float t = tokens[((size_t)b * SS + srow) * DD + d];
        xs[r][d] = (t - stats[0]) * stats[1] * g1[srow * DD + d] + be1[srow * DD + d];
    }
    __syncthreads();
    for (int o = tid; o < 768; o += 256) {
        int rr = o / 192;
        int rem = o % 192;
        int which = rem / 64;       // 0=q 1=k 2=v
        int he = rem % 64;
        int h = he >> 3, e = he & 7;
        int s2 = bx * 4 + rr;
        if (s2 >= SS) continue;
        const float* w = (which == 0) ? wq : (which == 1) ? wk : wv;
        const float* bias = (which == 0) ? bq : (which == 1) ? bk : bv;
        float acc = bias[he];
#pragma unroll
        for (int dd = 0; dd < 8; ++dd)
            acc += xs[rr][h * 8 + dd] * w[(h * 8 + dd) * 8 + e];
        if (which == 0) acc *= SCALE_LOG2E;
        short* dst = (which == 0) ? qb : (which == 1) ? kb : vb;
        dst[((size_t)(b * HH + h) * SP + s2) * 8 + e] = f2bf(acc);
    }
    if (bx == NTB - 1) {
        // zero K pad rows [SS, SP) for all heads of this batch: (SP-SS)*HH*8 = 15872 shorts
        for (int i = tid; i < (SP - SS) * HH * 8; i += 256) {
            int rr = i / (HH * 8);          // pad row index 0..30
            int he = i % (HH * 8);
            int hh = he >> 3, e = he & 7;
            kb[((size_t)(b * HH + hh) * SP + SS + rr) * 8 + e] = 0;
        }
    }
}

// ---------------- MFMA flash attention; CLS-row output + ln2-stat accumulation ----------------
// grid (3, HH, BB), 512 thr (8 waves).
// K read directly from global (L2); quads 1-3 broadcast the zeroed pad row ZROW.
// R12 restructure: swapped-operand QK^T (S^T = mfma(K, Q)) makes the PV A-fragment
//   lane-local — P goes registers -> exp2 -> cvt_pk -> PV MFMA with ZERO LDS ops for P.
//   V staged with matching sigmaPV permutation; 1 ds_read_b128 per chunk total.
// R15/R16: scratch spill chased down — launch_bounds relaxed to (512,4) AND chunk loop
//   unroll(disable) + branchless rotated prefetch. Result: WRITE 56 KB, VGPR 24,
//   54.2 µs. Lesson: the allocator splits the 128 budget into 64 arch + 64 accum for
//   MFMA kernels; compiler unrolling doubled live state past 64 -> per-iter spill.
// R17: counters show latency-bound (VALU 45%, Mfma 19%, occ 52% — nothing saturated).
//   K(ch+1) load issued ~100 own-wave cycles before its use (L2 latency ~200-300);
//   vf ds_read used ~50 cyc after issue (LDS latency ~120). All waves run the same
//   phase, so stalls align. Fix: K prefetch 2 chunks deep (ka0/kb0 <- ka1/kb1 rotate),
//   V prefetch 1 chunk deep (vfn). Load-to-use distance becomes >= 1 full iteration.
//   Dead-loads: K runs 2 chunks past the bh slice (lands in adjacent vb region,
//   allocated, never consumed); V's last prefetch reads <= 48 B past VTs into Es
//   (same LDS block, dead value). VGPR ~24 -> ~56, still under the 64 arch half.
__global__ __launch_bounds__(512, 4)
void k_attn(const short* __restrict__ qb, const short* __restrict__ kb, const short* __restrict__ vb,
            const float* __restrict__ tokens, float* __restrict__ out0,
            float* __restrict__ sum2, float* __restrict__ sumsq2) {
    __shared__ __align__(16) short VTs[9 * VTROW];   // 19152 B: V^T rows [e][perm-idx]; row 8 = ones(t<SS)
    __shared__ __align__(16) float Es[8 * 256];      // 8192 B: per-wave O spill; reused for final reduction
    int h = blockIdx.y, b = blockIdx.z;
    int bh = b * HH + h;
    int tid = threadIdx.x;
    int wave = tid >> 6, lane = tid & 63;
    int col = lane & 15, quad = lane >> 4;

    bf16x8 z8 = {0, 0, 0, 0, 0, 0, 0, 0};
    {   // stage V^T k-permuted: VTs[e][32*ch + v] = V[32*ch + sigmaPV(v)][e].
        // row 8 = softmax-denominator ones (0 where t >= SS: excludes pad P=1 terms).
        const bf16x8* vg = (const bf16x8*)(vb + (size_t)bh * SP * 8);
        for (int i = tid; i < SP; i += 512) {
            int t = (i & ~31) | sigmaPV(i & 31);
            if (t < SS) {
                bf16x8 row = vg[t];
#pragma unroll
                for (int e = 0; e < 8; ++e) VTs[e * VTROW + i] = row[e];
                VTs[8 * VTROW + i] = (short)0x3F80;   // bf16 1.0
            } else {
#pragma unroll
                for (int e = 0; e < 9; ++e) VTs[e * VTROW + i] = 0;
            }
        }
    }
    __syncthreads();

    // K A-frag straight from global: quad0 lanes walk rows t0+col / t0+col+16;
    // quads 1-3 read the zeroed pad row (same address across lanes -> broadcast).
    const short* kg = kb + (size_t)bh * SP * 8;
    const short* kp0 = kg + ((quad == 0) ? col * 8 : ZROW * 8);
    const int kstep = (quad == 0) ? 256 : 0;     // shorts per 32-t chunk
    const int koff16 = (quad == 0) ? 128 : 0;
    // V B-frag: lane col -> VT row e; cols 9-15 read the ones row (their O columns
    // are computed but never read in the epilogue — harmless finite values)
    const short* vbase_l = VTs + (col < 9 ? col : 8) * VTROW + quad * 8;
    float* Ef = Es + wave * 256;

    float lsum = 0.f, lssq = 0.f;
    int slot = blockIdx.x * 8 + wave;   // 0..23

    for (int qt = slot; qt < NQT; qt += 24) {
        bf16x8 qfrag = z8;
        if (quad == 0) qfrag = *(const bf16x8*)(qb + ((size_t)bh * SP + qt * 16 + col) * 8);
        f32x4 o = {0.f, 0.f, 0.f, 0.f};
        const f32x4 zz = {0.f, 0.f, 0.f, 0.f};
        // K prefetch 2 deep; V prefetch 1 deep
        const short* kptr = kp0;
        bf16x8 ka0 = *(const bf16x8*)kptr;
        bf16x8 kb0 = *(const bf16x8*)(kptr + koff16);
        kptr += kstep;
        bf16x8 ka1 = *(const bf16x8*)kptr;
        bf16x8 kb1 = *(const bf16x8*)(kptr + koff16);
        kptr += kstep;                                   // points at chunk ch+2
        const short* vptr = vbase_l;
        bf16x8 vf = *(const bf16x8*)vptr;                // V(0)
#pragma clang loop unroll(disable)
        for (int ch = 0; ch < NCH; ++ch) {
            vptr += 32;
            bf16x8 vfn = *(const bf16x8*)vptr;           // V(ch+1) — issued a full iter early
            f32x4 s0 = __builtin_amdgcn_mfma_f32_16x16x32_bf16(ka0, qfrag, zz, 0, 0, 0);
            f32x4 s1 = __builtin_amdgcn_mfma_f32_16x16x32_bf16(kb0, qfrag, zz, 0, 0, 0);
            ka0 = ka1; kb0 = kb1;                        // register rotate
            ka1 = *(const bf16x8*)kptr;                  // K(ch+2) — issued 2 iters early
            kb1 = *(const bf16x8*)(kptr + koff16);
            kptr += kstep;
            unsigned p0 = cvt_pk_bf16(exp2_fast(s0[0]), exp2_fast(s0[1]));
            unsigned p1 = cvt_pk_bf16(exp2_fast(s0[2]), exp2_fast(s0[3]));
            unsigned p2 = cvt_pk_bf16(exp2_fast(s1[0]), exp2_fast(s1[1]));
            unsigned p3 = cvt_pk_bf16(exp2_fast(s1[2]), exp2_fast(s1[3]));
            u32x4 pu = {p0, p1, p2, p3};
            o = __builtin_amdgcn_mfma_f32_16x16x32_bf16(__builtin_bit_cast(bf16x8, pu), vf, o, 0, 0, 0);
            vf = vfn;
        }
        // epilogue: spill O via per-wave scratch (col 8 = softmax denom l).
        // lane(col,quad) holds O[q=4*quad+r][e=col].
#pragma unroll
        for (int r = 0; r < 4; ++r) Ef[(quad * 4 + r) * 16 + col] = o[r];
#pragma unroll
        for (int pass = 0; pass < 2; ++pass) {
            int idx = lane + pass * 64;    // 16q x 8e
            int qq = idx >> 3, e = idx & 7;
            int qg = qt * 16 + qq;
            if (qg < SS) {
                float num = Ef[qq * 16 + e];
                float l = Ef[qq * 16 + 8];
                float ov = tokens[((size_t)b * SS + qg) * DD + h * 8 + e] + num / l;
                lsum += ov; lssq += ov * ov;
                if (qg == 0) out0[b * DD + h * 8 + e] = ov;
            }
        }
    }

    __syncthreads();
    Es[tid] = lsum; Es[512 + tid] = lssq;    // per-wave scratch dead; reuse for reduction
    __syncthreads();
    for (int off = 256; off > 0; off >>= 1) {
        if (tid < off) { Es[tid] += Es[tid + off]; Es[512 + tid] += Es[512 + tid + off]; }
        __syncthreads();
    }
    if (tid == 0) {
        atomicAdd(&sum2[b], Es[0]);
        atomicAdd(&sumsq2[b], Es[512]);
    }
}

// ---------------- final: ln2(row0) -> MLP(+relu) -> residual -> head -> softmax ----------------
__global__ void k_final(const float* __restrict__ out0, const float* __restrict__ sum2,
                        const float* __restrict__ sumsq2, const float* __restrict__ g2,
                        const float* __restrict__ be2, const float* __restrict__ w_enc,
                        const float* __restrict__ b_enc, const float* __restrict__ w_out,
                        const float* __restrict__ b_out, float* __restrict__ out) {
    int b = blockIdx.x;
    int tid = threadIdx.x;  // 64
    __shared__ float xn[DD], hsh[DD], logit[OUTD];
    float n = (float)SD;
    float mu = sum2[b] / n;
    float var = sumsq2[b] / n - mu * mu;
    float rs = rsqrtf(var + EPSF);
    float o = out0[b * DD + tid];
    xn[tid] = (o - mu) * rs * g2[tid] + be2[tid];
    __syncthreads();
    float acc = b_enc[tid];
#pragma unroll
    for (int d = 0; d < DD; ++d) acc += xn[d] * w_enc[d * DD + tid];
    hsh[tid] = o + fmaxf(acc, 0.f);
    __syncthreads();
    if (tid < OUTD) {
        float a = b_out[tid];
#pragma unroll
        for (int d = 0; d < DD; ++d) a += hsh[d] * w_out[d * OUTD + tid];
        logit[tid] = a;
    }
    __syncthreads();
    if (tid == 0) {
        float m = logit[0];
        for (int i = 1; i < OUTD; ++i) m = fmaxf(m, logit[i]);
        float p[OUTD]; float ssum = 0.f;
        for (int i = 0; i < OUTD; ++i) { p[i] = expf(logit[i] - m); ssum += p[i]; }
        for (int i = 0; i < OUTD; ++i) out[b * OUTD + i] = p[i] / ssum;
    }
}

extern "C" void kernel_launch(void* const* d_in, const int* in_sizes, int n_in,
                              void* d_out, int out_size, void* d_ws, size_t ws_size,
                              hipStream_t stream) {
    const float* images = (const float*)d_in[0];
    const float* w_map  = (const float*)d_in[1];
    const float* b_map  = (const float*)d_in[2];
    const float* cls    = (const float*)d_in[3];
    const float* g1     = (const float*)d_in[4];
    const float* be1    = (const float*)d_in[5];
    const float* wq     = (const float*)d_in[6];
    const float* bq     = (const float*)d_in[7];
    const float* wk     = (const float*)d_in[8];
    const float* bk     = (const float*)d_in[9];
    const float* wv     = (const float*)d_in[10];
    const float* bv     = (const float*)d_in[11];
    const float* g2     = (const float*)d_in[12];
    const float* be2    = (const float*)d_in[13];
    const float* w_enc  = (const float*)d_in[14];
    const float* b_enc  = (const float*)d_in[15];
    const float* w_out  = (const float*)d_in[16];
    const float* b_out  = (const float*)d_in[17];
    float* out = (float*)d_out;

    float* ws = (float*)d_ws;
    size_t off = 0;
    float* tokens = ws + off; off += (size_t)BB * SD;
    float* out0   = ws + off; off += BB * DD;
    float* part1  = ws + off; off += BB * NTB;
    float* partq1 = ws + off; off += BB * NTB;
    float* sum2   = ws + off; off += BB;
    float* sumsq2 = ws + off; off += BB;
    short* qb = (short*)(ws + off); off += (size_t)BB * HH * SP * 8 / 2;
    short* kb = (short*)(ws + off); off += (size_t)BB * HH * SP * 8 / 2;
    short* vb = (short*)(ws + off); off += (size_t)BB * HH * SP * 8 / 2;

    k_tokens<<<dim3(NTB, BB), 256, 0, stream>>>(images, w_map, b_map, cls, tokens,
                                                part1, partq1, sum2, sumsq2);
    k_qkv<<<dim3(NTB, BB), 256, 0, stream>>>(tokens, part1, partq1, g1, be1,
                                             wq, bq, wk, bk, wv, bv, qb, kb, vb);
    k_attn<<<dim3(3, HH, BB), 512, 0, stream>>>(qb, kb, vb, tokens, out0, sum2, sumsq2);
    k_final<<<BB, DD, 0, stream>>>(out0, sum2, sumsq2, g2, be2, w_enc, b_enc, w_out, b_out, out);
}

// Round 7
// 167.350 us; speedup vs baseline: 1.8458x; 1.0450x over previous
//
#include <hip/hip_runtime.h>
#include <math.h>

#define BB 32
#define SS 1025
#define DD 64
#define HH 8
#define IN_D 8
#define NPATCH 1024
#define OUTD 9
#define EPSF 1e-5f
#define SD (SS*DD)        // 65600
#define SP 1056           // padded seq = 33*32
#define NQT 65            // ceil(1025/16) q-tiles
#define NCH 33            // 1056/32 t-chunks
#define VTROW 1064        // VT LDS row stride (shorts)
#define NTB 257           // blocks per batch for token/stat kernels
#define ZROW 1055         // guaranteed-zero K row (pad, zeroed by k_qkv)

typedef __attribute__((ext_vector_type(8))) short bf16x8;
typedef __attribute__((ext_vector_type(4))) float f32x4;
typedef __attribute__((ext_vector_type(4))) unsigned u32x4;

// fold softmax scale 1/sqrt(8) and exp->exp2 into Q
#define SCALE_LOG2E (0.35355339059327378f * 1.4426950408889634f)

#if __has_builtin(__builtin_amdgcn_exp2f)
__device__ __forceinline__ float exp2_fast(float x) { return __builtin_amdgcn_exp2f(x); }
#else
__device__ __forceinline__ float exp2_fast(float x) {
    float r; asm("v_exp_f32 %0, %1" : "=v"(r) : "v"(x)); return r;
}
#endif

__device__ __forceinline__ short f2bf(float f) {
    union { float f; unsigned u; } a; a.f = f;
    unsigned r = a.u + 0x7FFFu + ((a.u >> 16) & 1u);  // RNE
    return (short)(r >> 16);
}

// packed f32->bf16 (RNE); lo lands in the LOW short — matches A-frag short order.
__device__ __forceinline__ unsigned cvt_pk_bf16(float lo, float hi) {
    unsigned r;
    asm("v_cvt_pk_bf16_f32 %0, %1, %2" : "=v"(r) : "v"(lo), "v"(hi));
    return r;
}

// PV virtual-k permutation: for A-frag slot v = 8*quad + j, the P value the lane
// already holds in registers is S^T tile row t = 4*quad + (j&3) + 16*(j>>2).
// sigma(v) = bit-shuffle {b2,b4,b3,b1,b0} — bijective on [0,32). V is staged with
// the same permutation so A and B agree on k-order (MFMA k-order is arbitrary).
__device__ __forceinline__ int sigmaPV(int v) {
    return ((v & 24) >> 1) | (v & 3) | ((v & 4) << 2);
}

// ---------------- tokens = [cls; patches@w_map+b_map] + pos; per-block partial ln1 stats ----------------
// R18: 8-barrier tree reduction -> wave shfl reduce + 1 barrier (saves ~6 barriers/block x 8224 blocks).
__global__ void k_tokens(const float* __restrict__ images, const float* __restrict__ w_map,
                         const float* __restrict__ b_map, const float* __restrict__ cls,
                         float* __restrict__ tokens, float* __restrict__ part1,
                         float* __restrict__ partq1, float* __restrict__ sum2,
                         float* __restrict__ sumsq2) {
    int b = blockIdx.y;
    int bx = blockIdx.x;
    int idx = bx * 256 + threadIdx.x;   // [0, SD)
    int tid = threadIdx.x;
    __shared__ float recip[64];
    __shared__ float wsred[8];
    if (tid < 64) {
        int j = tid;
        float div;
        if ((j & 1) == 0)
            div = powf(10000.0f, (float)j * (1.0f / 64.0f));
        else  // reference: 10000^(j-1)/64; overflow->inf -> recip 0 -> arg 0 -> cos=1 (matches f64)
            div = powf(10000.0f, (float)(j - 1)) * (1.0f / 64.0f);
        recip[j] = 1.0f / div;
    }
    __syncthreads();
    float lv = 0.f, lvv = 0.f;
    if (idx < SD) {
        int s = idx >> 6, j = idx & 63;
        float arg = (float)s * recip[j];
        float pv = (j & 1) ? __cosf(arg) : __sinf(arg);
        float v;
        if (s == 0) {
            v = cls[j];
        } else {
            const float* p = images + (size_t)b * (NPATCH * IN_D) + (size_t)(s - 1) * IN_D;
            float acc = b_map[j];
#pragma unroll
            for (int i = 0; i < IN_D; ++i) acc += p[i] * w_map[i * DD + j];
            v = acc;
        }
        v += pv;
        tokens[(size_t)b * SD + idx] = v;
        lv = v; lvv = v * v;
    }
    // wave64 shuffle reduce, then cross-wave combine (1 barrier)
    for (int off = 32; off > 0; off >>= 1) {
        lv += __shfl_down(lv, off, 64);
        lvv += __shfl_down(lvv, off, 64);
    }
    int wv = tid >> 6, ln = tid & 63;
    if (ln == 0) { wsred[wv] = lv; wsred[4 + wv] = lvv; }
    __syncthreads();
    if (tid == 0)  part1[b * NTB + bx]  = wsred[0] + wsred[1] + wsred[2] + wsred[3];
    if (tid == 64) partq1[b * NTB + bx] = wsred[4] + wsred[5] + wsred[6] + wsred[7];
    if (bx == 0) {          // zero the ln2 stat accumulators (k_attn adds later; stream-ordered)
        if (tid == 0) sum2[b] = 0.f;
        if (tid == 1) sumsq2[b] = 0.f;
    }
}

// ---------------- R18 new: reduce ln1 partials once per batch (was done redundantly by all 8224 k_qkv blocks) ----------------
__global__ void k_stats(const float* __restrict__ part1, const float* __restrict__ partq1,
                        float* __restrict__ stats) {
    int b = blockIdx.x, tid = threadIdx.x;   // 256 thr
    float s = 0.f, ss = 0.f;
    for (int i = tid; i < NTB; i += 256) { s += part1[b * NTB + i]; ss += partq1[b * NTB + i]; }
    for (int off = 32; off > 0; off >>= 1) {
        s += __shfl_down(s, off, 64);
        ss += __shfl_down(ss, off, 64);
    }
    __shared__ float wsred[8];
    int wv = tid >> 6, ln = tid & 63;
    if (ln == 0) { wsred[wv] = s; wsred[4 + wv] = ss; }
    __syncthreads();
    if (tid == 0) {
        float t  = wsred[0] + wsred[1] + wsred[2] + wsred[3];
        float tq = wsred[4] + wsred[5] + wsred[6] + wsred[7];
        float mu = t / (float)SD;
        float var = tq / (float)SD - mu * mu;
        stats[b * 2] = mu;
        stats[b * 2 + 1] = rsqrtf(var + EPSF);
    }
}

// ---------------- ln1 -> q,k,v in bf16, layout [bh][SP][8]; scale*log2e folded into q ----------------
// R18: reads precomputed stats (2 floats) instead of re-reducing 257 partials per block.
// Last block per batch additionally zeroes kb pad rows [SS, SP).
__global__ void k_qkv(const float* __restrict__ tokens, const float* __restrict__ stats,
                      const float* __restrict__ g1, const float* __restrict__ be1,
                      const float* __restrict__ wq, const float* __restrict__ bq,
                      const float* __restrict__ wk, const float* __restrict__ bk,
                      const float* __restrict__ wv, const float* __restrict__ bv,
                      short* __restrict__ qb, short* __restrict__ kb, short* __restrict__ vb) {
    int b = blockIdx.y, bx = blockIdx.x, tid = threadIdx.x;
    __shared__ float xs[4][DD];
    float mu = stats[b * 2];
    float rsig = stats[b * 2 + 1];
    int r = tid >> 6, d = tid & 63;
    int srow = bx * 4 + r;
    if (srow < SS) {
        float t = tokens[((size_t)b * SS + srow) * DD + d];
        xs[r][d] = (t - mu) * rsig * g1[srow * DD + d] + be1[srow * DD + d];
    }
    __syncthreads();
    for (int o = tid; o < 768; o += 256) {
        int rr = o / 192;
        int rem = o % 192;
        int which = rem / 64;       // 0=q 1=k 2=v
        int he = rem % 64;
        int h = he >> 3, e = he & 7;
        int s2 = bx * 4 + rr;
        if (s2 >= SS) continue;
        const float* w = (which == 0) ? wq : (which == 1) ? wk : wv;
        const float* bias = (which == 0) ? bq : (which == 1) ? bk : bv;
        float acc = bias[he];
#pragma unroll
        for (int dd = 0; dd < 8; ++dd)
            acc += xs[rr][h * 8 + dd] * w[(h * 8 + dd) * 8 + e];
        if (which == 0) acc *= SCALE_LOG2E;
        short* dst = (which == 0) ? qb : (which == 1) ? kb : vb;
        dst[((size_t)(b * HH + h) * SP + s2) * 8 + e] = f2bf(acc);
    }
    if (bx == NTB - 1) {
        // zero K pad rows [SS, SP) for all heads of this batch: (SP-SS)*HH*8 = 15872 shorts
        for (int i = tid; i < (SP - SS) * HH * 8; i += 256) {
            int rr = i / (HH * 8);          // pad row index 0..30
            int he = i % (HH * 8);
            int hh = he >> 3, e = he & 7;
            kb[((size_t)(b * HH + hh) * SP + SS + rr) * 8 + e] = 0;
        }
    }
}

// ---------------- MFMA flash attention; CLS-row output + ln2-stat accumulation ----------------
// grid (3, HH, BB), 512 thr (8 waves).
// R12: swapped-operand QK^T -> P register-local, 1 ds_read/chunk. R15/R16: spill killed
//   (launch_bounds (512,4) + unroll(disable) + branchless prefetch) -> 54 µs, VGPR 24.
// R17: deeper explicit prefetch was UNDONE by the compiler scheduler (VGPR stayed 24,
//   perf unchanged) — source-level prefetch depth within one chain isn't controllable.
// R18: latency-bound (VALU 45%, MFMA 19%, occ 52%, nothing saturated) -> attack with
//   ILP, not occupancy (grid-growth makes tile balance worse: critical path stays
//   3 tiles/wave). PAIR q-tiles (slot, slot+24): both chains share the SAME ka/kb and
//   vf fragments (ch-dependent only), so per chunk-iter: 1 ds_read + 2 K loads feed
//   4 QK MFMA + 16 exp + 8 cvt + 2 PV MFMA across two independent chains — stalls of
//   one chain covered by the other. Slots 0-16: {pair, single}; 17-23: {pair}.
//   Critical path 2.6 tile-equivalents (was 3) + ~2x stall coverage.
//   Reg estimate ~70 unified (arch ~46 + acc ~24) < 128 budget: no spill expected
//   (tripwire: WRITE_SIZE must stay ~56 KB).
#define PACK_PV(s0, s1, o, vf) do { \
    unsigned p0_ = cvt_pk_bf16(exp2_fast((s0)[0]), exp2_fast((s0)[1])); \
    unsigned p1_ = cvt_pk_bf16(exp2_fast((s0)[2]), exp2_fast((s0)[3])); \
    unsigned p2_ = cvt_pk_bf16(exp2_fast((s1)[0]), exp2_fast((s1)[1])); \
    unsigned p3_ = cvt_pk_bf16(exp2_fast((s1)[2]), exp2_fast((s1)[3])); \
    u32x4 pu_ = {p0_, p1_, p2_, p3_}; \
    (o) = __builtin_amdgcn_mfma_f32_16x16x32_bf16(__builtin_bit_cast(bf16x8, pu_), (vf), (o), 0, 0, 0); \
} while (0)

#define EPILOGUE(qt, o) do { \
    _Pragma("unroll") \
    for (int r_ = 0; r_ < 4; ++r_) Ef[(quad * 4 + r_) * 16 + col] = (o)[r_]; \
    _Pragma("unroll") \
    for (int pass_ = 0; pass_ < 2; ++pass_) { \
        int idx_ = lane + pass_ * 64; \
        int qq_ = idx_ >> 3, e_ = idx_ & 7; \
        int qg_ = (qt) * 16 + qq_; \
        if (qg_ < SS) { \
            float num_ = Ef[qq_ * 16 + e_]; \
            float l_ = Ef[qq_ * 16 + 8]; \
            float ov_ = tokens[((size_t)b * SS + qg_) * DD + h * 8 + e_] + num_ / l_; \
            lsum += ov_; lssq += ov_ * ov_; \
            if (qg_ == 0) out0[b * DD + h * 8 + e_] = ov_; \
        } \
    } \
} while (0)

__global__ __launch_bounds__(512, 4)
void k_attn(const short* __restrict__ qb, const short* __restrict__ kb, const short* __restrict__ vb,
            const float* __restrict__ tokens, float* __restrict__ out0,
            float* __restrict__ sum2, float* __restrict__ sumsq2) {
    __shared__ __align__(16) short VTs[9 * VTROW];   // 19152 B: V^T rows [e][perm-idx]; row 8 = ones(t<SS)
    __shared__ __align__(16) float Es[8 * 256];      // 8192 B: per-wave O spill; reused for final reduction
    int h = blockIdx.y, b = blockIdx.z;
    int bh = b * HH + h;
    int tid = threadIdx.x;
    int wave = tid >> 6, lane = tid & 63;
    int col = lane & 15, quad = lane >> 4;

    bf16x8 z8 = {0, 0, 0, 0, 0, 0, 0, 0};
    {   // stage V^T k-permuted: VTs[e][32*ch + v] = V[32*ch + sigmaPV(v)][e].
        // row 8 = softmax-denominator ones (0 where t >= SS: excludes pad P=1 terms).
        const bf16x8* vg = (const bf16x8*)(vb + (size_t)bh * SP * 8);
        for (int i = tid; i < SP; i += 512) {
            int t = (i & ~31) | sigmaPV(i & 31);
            if (t < SS) {
                bf16x8 row = vg[t];
#pragma unroll
                for (int e = 0; e < 8; ++e) VTs[e * VTROW + i] = row[e];
                VTs[8 * VTROW + i] = (short)0x3F80;   // bf16 1.0
            } else {
#pragma unroll
                for (int e = 0; e < 9; ++e) VTs[e * VTROW + i] = 0;
            }
        }
    }
    __syncthreads();

    // K A-frag straight from global: quad0 lanes walk rows t0+col / t0+col+16;
    // quads 1-3 read the zeroed pad row (same address across lanes -> broadcast).
    const short* kg = kb + (size_t)bh * SP * 8;
    const short* kp0 = kg + ((quad == 0) ? col * 8 : ZROW * 8);
    const int kstep = (quad == 0) ? 256 : 0;     // shorts per 32-t chunk
    const int koff16 = (quad == 0) ? 128 : 0;
    // V B-frag: lane col -> VT row e; cols 9-15 read the ones row (their O columns
    // are computed but never read in the epilogue — harmless finite values)
    const short* vbase_l = VTs + (col < 9 ? col : 8) * VTROW + quad * 8;
    float* Ef = Es + wave * 256;

    float lsum = 0.f, lssq = 0.f;
    int slot = blockIdx.x * 8 + wave;   // 0..23

    const f32x4 zz = {0.f, 0.f, 0.f, 0.f};
    for (int qt0 = slot; qt0 < NQT; qt0 += 48) {
        int qt1 = qt0 + 24;
        bf16x8 qf0 = z8;
        if (quad == 0) qf0 = *(const bf16x8*)(qb + ((size_t)bh * SP + qt0 * 16 + col) * 8);
        if (qt1 < NQT) {
            // -------- paired: two q-tiles share ka/kb/vf --------
            bf16x8 qf1 = z8;
            if (quad == 0) qf1 = *(const bf16x8*)(qb + ((size_t)bh * SP + qt1 * 16 + col) * 8);
            f32x4 oa = zz, ob = zz;
            const short* kptr = kp0;
            bf16x8 ka = *(const bf16x8*)kptr;
            bf16x8 kbx = *(const bf16x8*)(kptr + koff16);
            kptr += kstep;
            const short* vptr = vbase_l;
#pragma clang loop unroll(disable)
            for (int ch = 0; ch < NCH; ++ch) {
                bf16x8 vf = *(const bf16x8*)vptr;
                vptr += 32;
                f32x4 s0a = __builtin_amdgcn_mfma_f32_16x16x32_bf16(ka, qf0, zz, 0, 0, 0);
                f32x4 s1a = __builtin_amdgcn_mfma_f32_16x16x32_bf16(kbx, qf0, zz, 0, 0, 0);
                f32x4 s0b = __builtin_amdgcn_mfma_f32_16x16x32_bf16(ka, qf1, zz, 0, 0, 0);
                f32x4 s1b = __builtin_amdgcn_mfma_f32_16x16x32_bf16(kbx, qf1, zz, 0, 0, 0);
                ka = *(const bf16x8*)kptr;               // rotated prefetch (dead-load on last
                kbx = *(const bf16x8*)(kptr + koff16);   //  iter lands in adjacent vb region)
                kptr += kstep;
                PACK_PV(s0a, s1a, oa, vf);
                PACK_PV(s0b, s1b, ob, vf);
            }
            EPILOGUE(qt0, oa);
            EPILOGUE(qt1, ob);
        } else {
            // -------- single tail tile --------
            f32x4 oa = zz;
            const short* kptr = kp0;
            bf16x8 ka = *(const bf16x8*)kptr;
            bf16x8 kbx = *(const bf16x8*)(kptr + koff16);
            kptr += kstep;
            const short* vptr = vbase_l;
#pragma clang loop unroll(disable)
            for (int ch = 0; ch < NCH; ++ch) {
                bf16x8 vf = *(const bf16x8*)vptr;
                vptr += 32;
                f32x4 s0a = __builtin_amdgcn_mfma_f32_16x16x32_bf16(ka, qf0, zz, 0, 0, 0);
                f32x4 s1a = __builtin_amdgcn_mfma_f32_16x16x32_bf16(kbx, qf0, zz, 0, 0, 0);
                ka = *(const bf16x8*)kptr;
                kbx = *(const bf16x8*)(kptr + koff16);
                kptr += kstep;
                PACK_PV(s0a, s1a, oa, vf);
            }
            EPILOGUE(qt0, oa);
        }
    }

    __syncthreads();
    Es[tid] = lsum; Es[512 + tid] = lssq;    // per-wave scratch dead; reuse for reduction
    __syncthreads();
    for (int off = 256; off > 0; off >>= 1) {
        if (tid < off) { Es[tid] += Es[tid + off]; Es[512 + tid] += Es[512 + tid + off]; }
        __syncthreads();
    }
    if (tid == 0) {
        atomicAdd(&sum2[b], Es[0]);
        atomicAdd(&sumsq2[b], Es[512]);
    }
}

// ---------------- final: ln2(row0) -> MLP(+relu) -> residual -> head -> softmax ----------------
__global__ void k_final(const float* __restrict__ out0, const float* __restrict__ sum2,
                        const float* __restrict__ sumsq2, const float* __restrict__ g2,
                        const float* __restrict__ be2, const float* __restrict__ w_enc,
                        const float* __restrict__ b_enc, const float* __restrict__ w_out,
                        const float* __restrict__ b_out, float* __restrict__ out) {
    int b = blockIdx.x;
    int tid = threadIdx.x;  // 64
    __shared__ float xn[DD], hsh[DD], logit[OUTD];
    float n = (float)SD;
    float mu = sum2[b] / n;
    float var = sumsq2[b] / n - mu * mu;
    float rs = rsqrtf(var + EPSF);
    float o = out0[b * DD + tid];
    xn[tid] = (o - mu) * rs * g2[tid] + be2[tid];
    __syncthreads();
    float acc = b_enc[tid];
#pragma unroll
    for (int d = 0; d < DD; ++d) acc += xn[d] * w_enc[d * DD + tid];
    hsh[tid] = o + fmaxf(acc, 0.f);
    __syncthreads();
    if (tid < OUTD) {
        float a = b_out[tid];
#pragma unroll
        for (int d = 0; d < DD; ++d) a += hsh[d] * w_out[d * OUTD + tid];
        logit[tid] = a;
    }
    __syncthreads();
    if (tid == 0) {
        float m = logit[0];
        for (int i = 1; i < OUTD; ++i) m = fmaxf(m, logit[i]);
        float p[OUTD]; float ssum = 0.f;
        for (int i = 0; i < OUTD; ++i) { p[i] = expf(logit[i] - m); ssum += p[i]; }
        for (int i = 0; i < OUTD; ++i) out[b * OUTD + i] = p[i] / ssum;
    }
}

extern "C" void kernel_launch(void* const* d_in, const int* in_sizes, int n_in,
                              void* d_out, int out_size, void* d_ws, size_t ws_size,
                              hipStream_t stream) {
    const float* images = (const float*)d_in[0];
    const float* w_map  = (const float*)d_in[1];
    const float* b_map  = (const float*)d_in[2];
    const float* cls    = (const float*)d_in[3];
    const float* g1     = (const float*)d_in[4];
    const float* be1    = (const float*)d_in[5];
    const float* wq     = (const float*)d_in[6];
    const float* bq     = (const float*)d_in[7];
    const float* wk     = (const float*)d_in[8];
    const float* bk     = (const float*)d_in[9];
    const float* wv     = (const float*)d_in[10];
    const float* bv     = (const float*)d_in[11];
    const float* g2     = (const float*)d_in[12];
    const float* be2    = (const float*)d_in[13];
    const float* w_enc  = (const float*)d_in[14];
    const float* b_enc  = (const float*)d_in[15];
    const float* w_out  = (const float*)d_in[16];
    const float* b_out  = (const float*)d_in[17];
    float* out = (float*)d_out;

    float* ws = (float*)d_ws;
    size_t off = 0;
    float* tokens = ws + off; off += (size_t)BB * SD;
    float* out0   = ws + off; off += BB * DD;
    float* part1  = ws + off; off += BB * NTB;
    float* partq1 = ws + off; off += BB * NTB;
    float* sum2   = ws + off; off += BB;
    float* sumsq2 = ws + off; off += BB;
    float* stats  = ws + off; off += 2 * BB;
    short* qb = (short*)(ws + off); off += (size_t)BB * HH * SP * 8 / 2;
    short* kb = (short*)(ws + off); off += (size_t)BB * HH * SP * 8 / 2;
    short* vb = (short*)(ws + off); off += (size_t)BB * HH * SP * 8 / 2;

    k_tokens<<<dim3(NTB, BB), 256, 0, stream>>>(images, w_map, b_map, cls, tokens,
                                                part1, partq1, sum2, sumsq2);
    k_stats<<<BB, 256, 0, stream>>>(part1, partq1, stats);
    k_qkv<<<dim3(NTB, BB), 256, 0, stream>>>(tokens, stats, g1, be1,
                                             wq, bq, wk, bk, wv, bv, qb, kb, vb);
    k_attn<<<dim3(3, HH, BB), 512, 0, stream>>>(qb, kb, vb, tokens, out0, sum2, sumsq2);
    k_final<<<BB, DD, 0, stream>>>(out0, sum2, sumsq2, g2, be2, w_enc, b_enc, w_out, b_out, out);
}

// Round 8
// 164.504 us; speedup vs baseline: 1.8777x; 1.0173x over previous
//
#include <hip/hip_runtime.h>
#include <math.h>

#define BB 32
#define SS 1025
#define DD 64
#define HH 8
#define IN_D 8
#define NPATCH 1024
#define OUTD 9
#define EPSF 1e-5f
#define SD (SS*DD)        // 65600
#define SP 1056           // padded seq = 33*32
#define NQT 65            // ceil(1025/16) q-tiles
#define NCH 33            // 1056/32 t-chunks
#define VTROW 1064        // VT LDS row stride (shorts)
#define NTB 257           // blocks per batch for token/stat kernels
#define ZROW 1055         // guaranteed-zero K row (pad, zeroed by k_qkv)

typedef __attribute__((ext_vector_type(8))) short bf16x8;
typedef __attribute__((ext_vector_type(4))) float f32x4;
typedef __attribute__((ext_vector_type(4))) unsigned u32x4;

// fold softmax scale 1/sqrt(8) and exp->exp2 into Q
#define SCALE_LOG2E (0.35355339059327378f * 1.4426950408889634f)

#if __has_builtin(__builtin_amdgcn_exp2f)
__device__ __forceinline__ float exp2_fast(float x) { return __builtin_amdgcn_exp2f(x); }
#else
__device__ __forceinline__ float exp2_fast(float x) {
    float r; asm("v_exp_f32 %0, %1" : "=v"(r) : "v"(x)); return r;
}
#endif

__device__ __forceinline__ short f2bf(float f) {
    union { float f; unsigned u; } a; a.f = f;
    unsigned r = a.u + 0x7FFFu + ((a.u >> 16) & 1u);  // RNE
    return (short)(r >> 16);
}

// packed f32->bf16 (RNE); lo lands in the LOW short — matches A-frag short order.
__device__ __forceinline__ unsigned cvt_pk_bf16(float lo, float hi) {
    unsigned r;
    asm("v_cvt_pk_bf16_f32 %0, %1, %2" : "=v"(r) : "v"(lo), "v"(hi));
    return r;
}

// PV virtual-k permutation: for A-frag slot v = 8*quad + j, the P value the lane
// already holds in registers is S^T tile row t = 4*quad + (j&3) + 16*(j>>2).
// sigma(v) = bit-shuffle {b2,b4,b3,b1,b0} — bijective on [0,32). V is staged with
// the same permutation so A and B agree on k-order (MFMA k-order is arbitrary).
__device__ __forceinline__ int sigmaPV(int v) {
    return ((v & 24) >> 1) | (v & 3) | ((v & 4) << 2);
}

// ---------------- tokens = [cls; patches@w_map+b_map] + pos; per-block partial ln1 stats ----------------
// R18: 8-barrier tree reduction -> wave shfl reduce + 1 barrier.
__global__ void k_tokens(const float* __restrict__ images, const float* __restrict__ w_map,
                         const float* __restrict__ b_map, const float* __restrict__ cls,
                         float* __restrict__ tokens, float* __restrict__ part1,
                         float* __restrict__ partq1, float* __restrict__ sum2,
                         float* __restrict__ sumsq2) {
    int b = blockIdx.y;
    int bx = blockIdx.x;
    int idx = bx * 256 + threadIdx.x;   // [0, SD)
    int tid = threadIdx.x;
    __shared__ float recip[64];
    __shared__ float wsred[8];
    if (tid < 64) {
        int j = tid;
        float div;
        if ((j & 1) == 0)
            div = powf(10000.0f, (float)j * (1.0f / 64.0f));
        else  // reference: 10000^(j-1)/64; overflow->inf -> recip 0 -> arg 0 -> cos=1 (matches f64)
            div = powf(10000.0f, (float)(j - 1)) * (1.0f / 64.0f);
        recip[j] = 1.0f / div;
    }
    __syncthreads();
    float lv = 0.f, lvv = 0.f;
    if (idx < SD) {
        int s = idx >> 6, j = idx & 63;
        float arg = (float)s * recip[j];
        float pv = (j & 1) ? __cosf(arg) : __sinf(arg);
        float v;
        if (s == 0) {
            v = cls[j];
        } else {
            const float* p = images + (size_t)b * (NPATCH * IN_D) + (size_t)(s - 1) * IN_D;
            float acc = b_map[j];
#pragma unroll
            for (int i = 0; i < IN_D; ++i) acc += p[i] * w_map[i * DD + j];
            v = acc;
        }
        v += pv;
        tokens[(size_t)b * SD + idx] = v;
        lv = v; lvv = v * v;
    }
    // wave64 shuffle reduce, then cross-wave combine (1 barrier)
    for (int off = 32; off > 0; off >>= 1) {
        lv += __shfl_down(lv, off, 64);
        lvv += __shfl_down(lvv, off, 64);
    }
    int wv = tid >> 6, ln = tid & 63;
    if (ln == 0) { wsred[wv] = lv; wsred[4 + wv] = lvv; }
    __syncthreads();
    if (tid == 0)  part1[b * NTB + bx]  = wsred[0] + wsred[1] + wsred[2] + wsred[3];
    if (tid == 64) partq1[b * NTB + bx] = wsred[4] + wsred[5] + wsred[6] + wsred[7];
    if (bx == 0) {          // zero the ln2 stat accumulators (k_attn adds later; stream-ordered)
        if (tid == 0) sum2[b] = 0.f;
        if (tid == 1) sumsq2[b] = 0.f;
    }
}

// ---------------- reduce ln1 partials once per batch ----------------
__global__ void k_stats(const float* __restrict__ part1, const float* __restrict__ partq1,
                        float* __restrict__ stats) {
    int b = blockIdx.x, tid = threadIdx.x;   // 256 thr
    float s = 0.f, ss = 0.f;
    for (int i = tid; i < NTB; i += 256) { s += part1[b * NTB + i]; ss += partq1[b * NTB + i]; }
    for (int off = 32; off > 0; off >>= 1) {
        s += __shfl_down(s, off, 64);
        ss += __shfl_down(ss, off, 64);
    }
    __shared__ float wsred[8];
    int wv = tid >> 6, ln = tid & 63;
    if (ln == 0) { wsred[wv] = s; wsred[4 + wv] = ss; }
    __syncthreads();
    if (tid == 0) {
        float t  = wsred[0] + wsred[1] + wsred[2] + wsred[3];
        float tq = wsred[4] + wsred[5] + wsred[6] + wsred[7];
        float mu = t / (float)SD;
        float var = tq / (float)SD - mu * mu;
        stats[b * 2] = mu;
        stats[b * 2 + 1] = rsqrtf(var + EPSF);
    }
}

// ---------------- ln1 -> q,k,v in bf16, layout [bh][SP][8]; scale*log2e folded into q ----------------
__global__ void k_qkv(const float* __restrict__ tokens, const float* __restrict__ stats,
                      const float* __restrict__ g1, const float* __restrict__ be1,
                      const float* __restrict__ wq, const float* __restrict__ bq,
                      const float* __restrict__ wk, const float* __restrict__ bk,
                      const float* __restrict__ wv, const float* __restrict__ bv,
                      short* __restrict__ qb, short* __restrict__ kb, short* __restrict__ vb) {
    int b = blockIdx.y, bx = blockIdx.x, tid = threadIdx.x;
    __shared__ float xs[4][DD];
    float mu = stats[b * 2];
    float rsig = stats[b * 2 + 1];
    int r = tid >> 6, d = tid & 63;
    int srow = bx * 4 + r;
    if (srow < SS) {
        float t = tokens[((size_t)b * SS + srow) * DD + d];
        xs[r][d] = (t - mu) * rsig * g1[srow * DD + d] + be1[srow * DD + d];
    }
    __syncthreads();
    for (int o = tid; o < 768; o += 256) {
        int rr = o / 192;
        int rem = o % 192;
        int which = rem / 64;       // 0=q 1=k 2=v
        int he = rem % 64;
        int h = he >> 3, e = he & 7;
        int s2 = bx * 4 + rr;
        if (s2 >= SS) continue;
        const float* w = (which == 0) ? wq : (which == 1) ? wk : wv;
        const float* bias = (which == 0) ? bq : (which == 1) ? bk : bv;
        float acc = bias[he];
#pragma unroll
        for (int dd = 0; dd < 8; ++dd)
            acc += xs[rr][h * 8 + dd] * w[(h * 8 + dd) * 8 + e];
        if (which == 0) acc *= SCALE_LOG2E;
        short* dst = (which == 0) ? qb : (which == 1) ? kb : vb;
        dst[((size_t)(b * HH + h) * SP + s2) * 8 + e] = f2bf(acc);
    }
    if (bx == NTB - 1) {
        // zero K pad rows [SS, SP) for all heads of this batch: (SP-SS)*HH*8 = 15872 shorts
        for (int i = tid; i < (SP - SS) * HH * 8; i += 256) {
            int rr = i / (HH * 8);          // pad row index 0..30
            int he = i % (HH * 8);
            int hh = he >> 3, e = he & 7;
            kb[((size_t)(b * HH + hh) * SP + SS + rr) * 8 + e] = 0;
        }
    }
}

// ---------------- MFMA flash attention; CLS-row output + ln2-stat accumulation ----------------
// grid (3, HH, BB), 512 thr (8 waves).
// R12: swapped-operand QK^T -> P register-local, 1 ds_read/chunk. R15/R16: spill killed
//   (launch_bounds (512,4) + unroll(disable) + branchless rotated prefetch).
// R17: compiler undid deeper explicit prefetch (neutral). R18: q-tile PAIRING (+11%):
//   two chains share ka/kbx/vf -> 2x ILP per chunk-iter, no extra load traffic.
// R19: fuse each slot's ENTIRE tile set into ONE chunk loop (run_tiles<NT>):
//   17 slots x 3 tiles + 7 slots x 2 tiles. Replaces {pair-loop + single-loop} for
//   slots 0-16: critical path 33x(triple) vs 33x(pair)+33x(single) = -15% VALU units,
//   3 independent chains covering latency, and ONE K scan per slot instead of two.
//   Regs: qf 12 + s 24 + k 8 + vf 4 + o 12(acc) + misc ~14 ≈ 74 unified < 128 budget.
//   Arrays are static-indexed via full unroll (scratch rule); spill tripwire = WRITE_SIZE.
#define PACK_PV(s0, s1, o, vf) do { \
    unsigned p0_ = cvt_pk_bf16(exp2_fast((s0)[0]), exp2_fast((s0)[1])); \
    unsigned p1_ = cvt_pk_bf16(exp2_fast((s0)[2]), exp2_fast((s0)[3])); \
    unsigned p2_ = cvt_pk_bf16(exp2_fast((s1)[0]), exp2_fast((s1)[1])); \
    unsigned p3_ = cvt_pk_bf16(exp2_fast((s1)[2]), exp2_fast((s1)[3])); \
    u32x4 pu_ = {p0_, p1_, p2_, p3_}; \
    (o) = __builtin_amdgcn_mfma_f32_16x16x32_bf16(__builtin_bit_cast(bf16x8, pu_), (vf), (o), 0, 0, 0); \
} while (0)

template<int NT>
__device__ __forceinline__ void run_tiles(
    int slot, const short* __restrict__ qb, size_t bhSP,
    const short* kp0, int kstep, int koff16, const short* vbase_l,
    float* Ef, const float* __restrict__ tokens, float* __restrict__ out0,
    int b, int h, int lane, int col, int quad, float& lsum, float& lssq)
{
    const f32x4 zz = {0.f, 0.f, 0.f, 0.f};
    bf16x8 z8 = {0, 0, 0, 0, 0, 0, 0, 0};
    bf16x8 qf[NT];
    f32x4 o[NT];
#pragma unroll
    for (int t = 0; t < NT; ++t) {
        qf[t] = z8;
        if (quad == 0)
            qf[t] = *(const bf16x8*)(qb + (bhSP + (size_t)((slot + 24 * t) * 16 + col)) * 8);
        o[t] = zz;
    }
    const short* kptr = kp0;
    bf16x8 ka = *(const bf16x8*)kptr;
    bf16x8 kbx = *(const bf16x8*)(kptr + koff16);
    kptr += kstep;
    const short* vptr = vbase_l;
#pragma clang loop unroll(disable)
    for (int ch = 0; ch < NCH; ++ch) {
        bf16x8 vf = *(const bf16x8*)vptr;            // the ONLY LDS op in the loop
        vptr += 32;
        f32x4 s0[NT], s1[NT];
#pragma unroll
        for (int t = 0; t < NT; ++t) {
            s0[t] = __builtin_amdgcn_mfma_f32_16x16x32_bf16(ka, qf[t], zz, 0, 0, 0);
            s1[t] = __builtin_amdgcn_mfma_f32_16x16x32_bf16(kbx, qf[t], zz, 0, 0, 0);
        }
        ka = *(const bf16x8*)kptr;                   // rotated prefetch (dead-load on last
        kbx = *(const bf16x8*)(kptr + koff16);       //  iter lands in adjacent ws region)
        kptr += kstep;
#pragma unroll
        for (int t = 0; t < NT; ++t) PACK_PV(s0[t], s1[t], o[t], vf);
    }
#pragma unroll
    for (int t = 0; t < NT; ++t) {
        int qt = slot + 24 * t;
        // epilogue: spill O via per-wave scratch (col 8 = softmax denom l).
        // lane(col,quad) holds O[q=4*quad+r][e=col].
#pragma unroll
        for (int r = 0; r < 4; ++r) Ef[(quad * 4 + r) * 16 + col] = o[t][r];
#pragma unroll
        for (int pass = 0; pass < 2; ++pass) {
            int idx = lane + pass * 64;    // 16q x 8e
            int qq = idx >> 3, e = idx & 7;
            int qg = qt * 16 + qq;
            if (qg < SS) {
                float num = Ef[qq * 16 + e];
                float l = Ef[qq * 16 + 8];
                float ov = tokens[((size_t)b * SS + qg) * DD + h * 8 + e] + num / l;
                lsum += ov; lssq += ov * ov;
                if (qg == 0) out0[b * DD + h * 8 + e] = ov;
            }
        }
    }
}

__global__ __launch_bounds__(512, 4)
void k_attn(const short* __restrict__ qb, const short* __restrict__ kb, const short* __restrict__ vb,
            const float* __restrict__ tokens, float* __restrict__ out0,
            float* __restrict__ sum2, float* __restrict__ sumsq2) {
    __shared__ __align__(16) short VTs[9 * VTROW];   // 19152 B: V^T rows [e][perm-idx]; row 8 = ones(t<SS)
    __shared__ __align__(16) float Es[8 * 256];      // 8192 B: per-wave O spill; reused for final reduction
    int h = blockIdx.y, b = blockIdx.z;
    int bh = b * HH + h;
    int tid = threadIdx.x;
    int wave = tid >> 6, lane = tid & 63;
    int col = lane & 15, quad = lane >> 4;

    {   // stage V^T k-permuted: VTs[e][32*ch + v] = V[32*ch + sigmaPV(v)][e].
        // row 8 = softmax-denominator ones (0 where t >= SS: excludes pad P=1 terms).
        const bf16x8* vg = (const bf16x8*)(vb + (size_t)bh * SP * 8);
        for (int i = tid; i < SP; i += 512) {
            int t = (i & ~31) | sigmaPV(i & 31);
            if (t < SS) {
                bf16x8 row = vg[t];
#pragma unroll
                for (int e = 0; e < 8; ++e) VTs[e * VTROW + i] = row[e];
                VTs[8 * VTROW + i] = (short)0x3F80;   // bf16 1.0
            } else {
#pragma unroll
                for (int e = 0; e < 9; ++e) VTs[e * VTROW + i] = 0;
            }
        }
    }
    __syncthreads();

    // K A-frag straight from global: quad0 lanes walk rows t0+col / t0+col+16;
    // quads 1-3 read the zeroed pad row (same address across lanes -> broadcast).
    const short* kg = kb + (size_t)bh * SP * 8;
    const short* kp0 = kg + ((quad == 0) ? col * 8 : ZROW * 8);
    const int kstep = (quad == 0) ? 256 : 0;     // shorts per 32-t chunk
    const int koff16 = (quad == 0) ? 128 : 0;
    // V B-frag: lane col -> VT row e; cols 9-15 read the ones row (their O columns
    // are computed but never read in the epilogue — harmless finite values)
    const short* vbase_l = VTs + (col < 9 ? col : 8) * VTROW + quad * 8;
    float* Ef = Es + wave * 256;

    float lsum = 0.f, lssq = 0.f;
    int slot = blockIdx.x * 8 + wave;   // 0..23
    size_t bhSP = (size_t)bh * SP;

    if (slot + 48 < NQT)    // slots 0-16: 3 tiles fused; slots 17-23: 2 tiles fused
        run_tiles<3>(slot, qb, bhSP, kp0, kstep, koff16, vbase_l, Ef, tokens, out0,
                     b, h, lane, col, quad, lsum, lssq);
    else
        run_tiles<2>(slot, qb, bhSP, kp0, kstep, koff16, vbase_l, Ef, tokens, out0,
                     b, h, lane, col, quad, lsum, lssq);

    __syncthreads();
    Es[tid] = lsum; Es[512 + tid] = lssq;    // per-wave scratch dead; reuse for reduction
    __syncthreads();
    for (int off = 256; off > 0; off >>= 1) {
        if (tid < off) { Es[tid] += Es[tid + off]; Es[512 + tid] += Es[512 + tid + off]; }
        __syncthreads();
    }
    if (tid == 0) {
        atomicAdd(&sum2[b], Es[0]);
        atomicAdd(&sumsq2[b], Es[512]);
    }
}

// ---------------- final: ln2(row0) -> MLP(+relu) -> residual -> head -> softmax ----------------
__global__ void k_final(const float* __restrict__ out0, const float* __restrict__ sum2,
                        const float* __restrict__ sumsq2, const float* __restrict__ g2,
                        const float* __restrict__ be2, const float* __restrict__ w_enc,
                        const float* __restrict__ b_enc, const float* __restrict__ w_out,
                        const float* __restrict__ b_out, float* __restrict__ out) {
    int b = blockIdx.x;
    int tid = threadIdx.x;  // 64
    __shared__ float xn[DD], hsh[DD], logit[OUTD];
    float n = (float)SD;
    float mu = sum2[b] / n;
    float var = sumsq2[b] / n - mu * mu;
    float rs = rsqrtf(var + EPSF);
    float o = out0[b * DD + tid];
    xn[tid] = (o - mu) * rs * g2[tid] + be2[tid];
    __syncthreads();
    float acc = b_enc[tid];
#pragma unroll
    for (int d = 0; d < DD; ++d) acc += xn[d] * w_enc[d * DD + tid];
    hsh[tid] = o + fmaxf(acc, 0.f);
    __syncthreads();
    if (tid < OUTD) {
        float a = b_out[tid];
#pragma unroll
        for (int d = 0; d < DD; ++d) a += hsh[d] * w_out[d * OUTD + tid];
        logit[tid] = a;
    }
    __syncthreads();
    if (tid == 0) {
        float m = logit[0];
        for (int i = 1; i < OUTD; ++i) m = fmaxf(m, logit[i]);
        float p[OUTD]; float ssum = 0.f;
        for (int i = 0; i < OUTD; ++i) { p[i] = expf(logit[i] - m); ssum += p[i]; }
        for (int i = 0; i < OUTD; ++i) out[b * OUTD + i] = p[i] / ssum;
    }
}

extern "C" void kernel_launch(void* const* d_in, const int* in_sizes, int n_in,
                              void* d_out, int out_size, void* d_ws, size_t ws_size,
                              hipStream_t stream) {
    const float* images = (const float*)d_in[0];
    const float* w_map  = (const float*)d_in[1];
    const float* b_map  = (const float*)d_in[2];
    const float* cls    = (const float*)d_in[3];
    const float* g1     = (const float*)d_in[4];
    const float* be1    = (const float*)d_in[5];
    const float* wq     = (const float*)d_in[6];
    const float* bq     = (const float*)d_in[7];
    const float* wk     = (const float*)d_in[8];
    const float* bk     = (const float*)d_in[9];
    const float* wv     = (const float*)d_in[10];
    const float* bv     = (const float*)d_in[11];
    const float* g2     = (const float*)d_in[12];
    const float* be2    = (const float*)d_in[13];
    const float* w_enc  = (const float*)d_in[14];
    const float* b_enc  = (const float*)d_in[15];
    const float* w_out  = (const float*)d_in[16];
    const float* b_out  = (const float*)d_in[17];
    float* out = (float*)d_out;

    float* ws = (float*)d_ws;
    size_t off = 0;
    float* tokens = ws + off; off += (size_t)BB * SD;
    float* out0   = ws + off; off += BB * DD;
    float* part1  = ws + off; off += BB * NTB;
    float* partq1 = ws + off; off += BB * NTB;
    float* sum2   = ws + off; off += BB;
    float* sumsq2 = ws + off; off += BB;
    float* stats  = ws + off; off += 2 * BB;
    short* qb = (short*)(ws + off); off += (size_t)BB * HH * SP * 8 / 2;
    short* kb = (short*)(ws + off); off += (size_t)BB * HH * SP * 8 / 2;
    short* vb = (short*)(ws + off); off += (size_t)BB * HH * SP * 8 / 2;

    k_tokens<<<dim3(NTB, BB), 256, 0, stream>>>(images, w_map, b_map, cls, tokens,
                                                part1, partq1, sum2, sumsq2);
    k_stats<<<BB, 256, 0, stream>>>(part1, partq1, stats);
    k_qkv<<<dim3(NTB, BB), 256, 0, stream>>>(tokens, stats, g1, be1,
                                             wq, bq, wk, bk, wv, bv, qb, kb, vb);
    k_attn<<<dim3(3, HH, BB), 512, 0, stream>>>(qb, kb, vb, tokens, out0, sum2, sumsq2);
    k_final<<<BB, DD, 0, stream>>>(out0, sum2, sumsq2, g2, be2, w_enc, b_enc, w_out, b_out, out);
}